// Round 18
// baseline (1686.024 us; speedup 1.0000x reference)
//
#include <hip/hip_runtime.h>
#include <hip/hip_bf16.h>

using short8 = __attribute__((ext_vector_type(8))) short;
using f32x4  = __attribute__((ext_vector_type(4))) float;

#define DEV __device__ __forceinline__
#define LDB 264

DEV float bu(unsigned short u) { union { unsigned int i; float f; } z; z.i = (unsigned)u << 16; return z.f; }
DEV unsigned short fb(float f) { __hip_bfloat16 h = __float2bfloat16(f); return *reinterpret_cast<unsigned short*>(&h); }

DEV float gelu_f(float v) {
    float u = 0.7978845608028654f * (v + 0.044715f * v * v * v);
    u = fminf(fmaxf(u, -20.f), 20.f);
    float e = __expf(2.f * u);
    return 0.5f * v * (1.f + (e - 1.f) / (e + 1.f));
}

// ---------------- weight prep: WT[n][k] = bf16(W[k][n]) ----------------
__global__ void k_wt(const float* __restrict__ W, unsigned short* __restrict__ WT, int K, int N) {
    int i = blockIdx.x * 256 + threadIdx.x;
    if (i >= N * K) return;
    int n = i / K, k = i % K;
    WT[i] = fb(W[(size_t)k * N + n]);
}

// ---------------------------------------------------------------------------------------
// Per-wave MFMA: acc[NT][4] += A[64 rows][256](bf16 LDS, ld LDB) @ B[(nt0+i)*16+fl][ldB]^T
// A-frag: row=m*16+fl, k=fh*8+j. D: row=m*16+fh*4+r, col=(nt0+i)*16+fl  [m89-verified].
// ---------------------------------------------------------------------------------------
template<int NT, int KG>
DEV void mm64(const unsigned short* __restrict__ A, const unsigned short* __restrict__ B,
              int ldB, int koff, f32x4 acc[NT][4], int nt0, int lane)
{
    const int fl = lane & 15, fh = lane >> 4;
#pragma unroll
    for (int kg = 0; kg < KG; ++kg) {
        short8 b[NT];
#pragma unroll
        for (int i = 0; i < NT; ++i)
            b[i] = *(const short8*)(B + (size_t)((nt0 + i) * 16 + fl) * ldB + koff + kg * 32 + fh * 8);
        short8 a[4];
#pragma unroll
        for (int m = 0; m < 4; ++m)
            a[m] = *(const short8*)(A + (m * 16 + fl) * LDB + kg * 32 + fh * 8);
#pragma unroll
        for (int i = 0; i < NT; ++i)
#pragma unroll
            for (int m = 0; m < 4; ++m)
                acc[i][m] = __builtin_amdgcn_mfma_f32_16x16x32_bf16(a[m], b[i], acc[i][m], 0, 0, 0);
    }
}

// Merged QKV: one pass over A (xb loaded ONCE per kg), 3 accumulator sets.
DEV void mm64_qkv(const unsigned short* __restrict__ A,
                  const unsigned short* __restrict__ wq, const unsigned short* __restrict__ wk,
                  const unsigned short* __restrict__ wv,
                  f32x4 aq[2][4], f32x4 ak[2][4], f32x4 av[2][4], int nt0, int lane)
{
    const int fl = lane & 15, fh = lane >> 4;
#pragma unroll
    for (int kg = 0; kg < 8; ++kg) {
        short8 a[4];
#pragma unroll
        for (int m = 0; m < 4; ++m)
            a[m] = *(const short8*)(A + (m * 16 + fl) * LDB + kg * 32 + fh * 8);
        short8 bq[2], bk[2], bv[2];
#pragma unroll
        for (int i = 0; i < 2; ++i) {
            size_t rowoff = (size_t)((nt0 + i) * 16 + fl) * 256 + kg * 32 + fh * 8;
            bq[i] = *(const short8*)(wq + rowoff);
            bk[i] = *(const short8*)(wk + rowoff);
            bv[i] = *(const short8*)(wv + rowoff);
        }
#pragma unroll
        for (int i = 0; i < 2; ++i)
#pragma unroll
            for (int m = 0; m < 4; ++m) {
                aq[i][m] = __builtin_amdgcn_mfma_f32_16x16x32_bf16(a[m], bq[i], aq[i][m], 0, 0, 0);
                ak[i][m] = __builtin_amdgcn_mfma_f32_16x16x32_bf16(a[m], bk[i], ak[i][m], 0, 0, 0);
                av[i][m] = __builtin_amdgcn_mfma_f32_16x16x32_bf16(a[m], bv[i], av[i][m], 0, 0, 0);
            }
    }
}

template<int NT, bool GEL>
DEV void store_bf16(f32x4 acc[NT][4], unsigned short* __restrict__ D, int nt0, int lane) {
    const int fl = lane & 15, r0 = (lane >> 4) * 4;
#pragma unroll
    for (int i = 0; i < NT; ++i)
#pragma unroll
        for (int m = 0; m < 4; ++m)
#pragma unroll
            for (int r = 0; r < 4; ++r) {
                float v = acc[i][m][r];
                if (GEL) v = gelu_f(v);
                D[(m * 16 + r0 + r) * LDB + (nt0 + i) * 16 + fl] = fb(v);
            }
}

// f32 LayerNorm over register-resident xr; stats via shfl + red[64][8]; writes bf16 xb.
DEV void ln_reg(float xr[4][4][2], const float* __restrict__ s, const float* __restrict__ b,
                unsigned short* __restrict__ xb, float red[64][8],
                float* mrow, float* srow, int tid, int fl, int fh, int wid)
{
    float ps[4][4];
#pragma unroll
    for (int m = 0; m < 4; ++m)
#pragma unroll
        for (int r = 0; r < 4; ++r) {
            float v = xr[m][r][0] + xr[m][r][1];
#pragma unroll
            for (int off = 8; off >= 1; off >>= 1) v += __shfl_xor(v, off, 64);
            ps[m][r] = v;
        }
    if (fl == 0)
#pragma unroll
        for (int m = 0; m < 4; ++m)
#pragma unroll
            for (int r = 0; r < 4; ++r) red[m * 16 + fh * 4 + r][wid] = ps[m][r];
    __syncthreads();
    if (tid < 64) {
        float sum = 0.f;
#pragma unroll
        for (int j = 0; j < 8; ++j) sum += red[tid][j];
        mrow[tid] = sum * (1.f / 256.f);
    }
    __syncthreads();
#pragma unroll
    for (int m = 0; m < 4; ++m)
#pragma unroll
        for (int r = 0; r < 4; ++r) {
            float mu = mrow[m * 16 + fh * 4 + r];
            float d0 = xr[m][r][0] - mu, d1 = xr[m][r][1] - mu;
            float v = d0 * d0 + d1 * d1;
#pragma unroll
            for (int off = 8; off >= 1; off >>= 1) v += __shfl_xor(v, off, 64);
            ps[m][r] = v;
        }
    if (fl == 0)
#pragma unroll
        for (int m = 0; m < 4; ++m)
#pragma unroll
            for (int r = 0; r < 4; ++r) red[m * 16 + fh * 4 + r][wid] = ps[m][r];
    __syncthreads();
    if (tid < 64) {
        float sum = 0.f;
#pragma unroll
        for (int j = 0; j < 8; ++j) sum += red[tid][j];
        srow[tid] = rsqrtf(sum * (1.f / 256.f) + 1e-5f);
    }
    __syncthreads();
    float sc[2], bc[2];
#pragma unroll
    for (int i = 0; i < 2; ++i) { int c = (wid * 2 + i) * 16 + fl; sc[i] = s[c]; bc[i] = b[c]; }
#pragma unroll
    for (int m = 0; m < 4; ++m)
#pragma unroll
        for (int r = 0; r < 4; ++r) {
            int row = m * 16 + fh * 4 + r;
            float mu = mrow[row], rs = srow[row];
#pragma unroll
            for (int i = 0; i < 2; ++i) {
                float v = (xr[m][r][i] - mu) * rs * sc[i] + bc[i];
                xr[m][r][i] = v;
                xb[row * LDB + (wid * 2 + i) * 16 + fl] = fb(v);
            }
        }
    __syncthreads();
}

// ---------------------------------------------------------------------------------------
// Fused 2-layer encoder, M=64/block, f32 register residual, merged-QKV (V lands in xb),
// FF in 2 super-chunks (hidden 512 across S1+S2, NT=4 FF1).
// ---------------------------------------------------------------------------------------
template<bool WORD>
__global__ __launch_bounds__(512, 2) void k_enc64(
    const int* __restrict__ inputs,
    const float* __restrict__ char_emb, const float* __restrict__ pos_emb,
    const unsigned short* __restrict__ qkvT, const unsigned short* __restrict__ woT,
    const unsigned short* __restrict__ w1T,  const unsigned short* __restrict__ w2T,
    const float* __restrict__ ln1s, const float* __restrict__ ln1b,
    const float* __restrict__ ln2s, const float* __restrict__ ln2b,
    const int* __restrict__ w2n, const int* __restrict__ wpos,
    float* __restrict__ NE, float* __restrict__ out)
{
    constexpr int T = WORD ? 16 : 8;
    const int blk = blockIdx.x, tid = threadIdx.x;
    const int lane = tid & 63, wid = tid >> 6;
    const int fl = lane & 15, fh = lane >> 4;
    __shared__ __attribute__((aligned(16))) unsigned short xb[64 * LDB];  // A-operand / V
    __shared__ __attribute__((aligned(16))) unsigned short S1[64 * LDB];  // Q->o / hidden lo
    __shared__ __attribute__((aligned(16))) unsigned short S2[64 * LDB];  // K / hidden hi
    __shared__ float red[64][8];
    __shared__ float mrow[64], srow[64];
    __shared__ int ch[64];

    const int wl = WORD ? (tid >> 7) : (tid >> 6);
    const int hh = WORD ? ((tid >> 4) & 7) : ((tid >> 3) & 7);
    const int tt = WORD ? (tid & 15) : (tid & 7);
    const int arow = wl * T + tt;

    float xr[4][4][2];   // f32 residual stream (this thread's MFMA D-fragment cells)

    if (WORD) {
        if (tid < 64) ch[tid] = inputs[blk * 64 + tid];
        __syncthreads();
#pragma unroll
        for (int m = 0; m < 4; ++m)
#pragma unroll
            for (int r = 0; r < 4; ++r) {
                int row = m * 16 + fh * 4 + r;
#pragma unroll
                for (int i = 0; i < 2; ++i) {
                    int col = (wid * 2 + i) * 16 + fl;
                    float v = char_emb[(size_t)ch[row] * 256 + col] + pos_emb[(row & 15) * 256 + col];
                    xr[m][r][i] = v;
                    xb[row * LDB + col] = fb(v);
                }
            }
    } else {
#pragma unroll
        for (int m = 0; m < 4; ++m)
#pragma unroll
            for (int r = 0; r < 4; ++r) {
                int row = m * 16 + fh * 4 + r;
#pragma unroll
                for (int i = 0; i < 2; ++i) {
                    int col = (wid * 2 + i) * 16 + fl;
                    float v = NE[((size_t)blk * 64 + row) * 256 + col];
                    xr[m][r][i] = v;
                    xb[row * LDB + col] = fb(v);
                }
            }
    }
    __syncthreads();

    for (int l = 0; l < 2; ++l) {
        const unsigned short* wq = qkvT + (size_t)l * 196608;
        const unsigned short* wk = wq + 65536;
        const unsigned short* wv = wq + 131072;
        const unsigned short* wo = woT + (size_t)l * 65536;
        const unsigned short* w1 = w1T + (size_t)l * 262144;
        const unsigned short* w2 = w2T + (size_t)l * 262144;

        // ---- merged QKV: A loaded once/kg; Q->S1, K->S2, then V->xb (xb dead after) ----
        {
            f32x4 aq[2][4] = {}, ak[2][4] = {}, av[2][4] = {};
            mm64_qkv(xb, wq, wk, wv, aq, ak, av, wid * 2, lane);
            store_bf16<2, false>(aq, S1, wid * 2, lane);
            store_bf16<2, false>(ak, S2, wid * 2, lane);
            __syncthreads();                        // all xb reads done; Q,K visible
            store_bf16<2, false>(av, xb, wid * 2, lane);
            __syncthreads();                        // V visible
        }

        // ---- attention: q from S1, scores vs S2(K), PV from xb(V), o -> S1 own-cell ----
        {
            float q[32], p[T];
#pragma unroll
            for (int db = 0; db < 4; ++db) {
                short8 qv = *(const short8*)&S1[arow * LDB + hh * 32 + db * 8];
#pragma unroll
                for (int j = 0; j < 8; ++j) q[db * 8 + j] = bu((unsigned short)qv[j]);
            }
            float mx = -1e30f;
#pragma unroll
            for (int s = 0; s < T; ++s) {
                float dot = 0.f;
#pragma unroll
                for (int db = 0; db < 4; ++db) {
                    short8 kv = *(const short8*)&S2[(wl * T + s) * LDB + hh * 32 + db * 8];
#pragma unroll
                    for (int j = 0; j < 8; ++j) dot += q[db * 8 + j] * bu((unsigned short)kv[j]);
                }
                dot *= 0.17677669529663687f;
                if (WORD && ch[wl * 16 + s] == 0) dot = -1e9f;   // key-pad mask
                p[s] = dot; mx = fmaxf(mx, dot);
            }
            float sum = 0.f;
#pragma unroll
            for (int s = 0; s < T; ++s) { p[s] = __expf(p[s] - mx); sum += p[s]; }
            float inv = 1.f / sum;
#pragma unroll
            for (int s = 0; s < T; ++s) p[s] *= inv;

            float o[32];
#pragma unroll
            for (int j = 0; j < 32; ++j) o[j] = 0.f;
#pragma unroll
            for (int s = 0; s < T; ++s) {
                float ps = p[s];
#pragma unroll
                for (int db = 0; db < 4; ++db) {
                    short8 vv = *(const short8*)&xb[(wl * T + s) * LDB + hh * 32 + db * 8];
#pragma unroll
                    for (int j = 0; j < 8; ++j) o[db * 8 + j] += ps * bu((unsigned short)vv[j]);
                }
            }
#pragma unroll
            for (int db = 0; db < 4; ++db) {
                short8 ov;
#pragma unroll
                for (int j = 0; j < 8; ++j) ov[j] = (short)fb(o[db * 8 + j]);
                *(short8*)&S1[arow * LDB + hh * 32 + db * 8] = ov;   // own cell
            }
        }
        __syncthreads();

        // ---- Wo: S1(o) @ wo ; residual add in f32 regs; LN1 -> xb ----
        { f32x4 acc[2][4] = {}; mm64<2, 8>(S1, wo, 256, 0, acc, wid * 2, lane);
#pragma unroll
          for (int i = 0; i < 2; ++i)
#pragma unroll
              for (int m = 0; m < 4; ++m)
#pragma unroll
                  for (int r = 0; r < 4; ++r) xr[m][r][i] += acc[i][m][r]; }
        __syncthreads();
        ln_reg(xr, ln1s + l * 256, ln1b + l * 256, xb, red, mrow, srow, tid, fl, fh, wid);

        // ---- FF: 2 super-chunks of 512 hidden (S1+S2), FF1 NT=4, FF2 accumulates f32 ----
        {
            f32x4 acc2[2][4] = {};
#pragma unroll
            for (int sc = 0; sc < 2; ++sc) {
                f32x4 a1[4][4] = {};
                mm64<4, 8>(xb, w1, 256, 0, a1, sc * 32 + wid * 4, lane);
                const int r0 = fh * 4;
#pragma unroll
                for (int i = 0; i < 4; ++i) {
                    int tl = wid * 4 + i;                       // 0..31 within super-chunk
                    unsigned short* buf = (tl < 16) ? S1 : S2;
                    int col0 = (tl & 15) * 16 + fl;
#pragma unroll
                    for (int m = 0; m < 4; ++m)
#pragma unroll
                        for (int r = 0; r < 4; ++r)
                            buf[(m * 16 + r0 + r) * LDB + col0] = fb(gelu_f(a1[i][m][r]));
                }
                __syncthreads();
                mm64<2, 8>(S1, w2, 1024, sc * 512,       acc2, wid * 2, lane);
                mm64<2, 8>(S2, w2, 1024, sc * 512 + 256, acc2, wid * 2, lane);
                __syncthreads();
            }
#pragma unroll
            for (int i = 0; i < 2; ++i)
#pragma unroll
                for (int m = 0; m < 4; ++m)
#pragma unroll
                    for (int r = 0; r < 4; ++r) xr[m][r][i] += acc2[i][m][r];
        }
        ln_reg(xr, ln2s + l * 256, ln2b + l * 256, xb, red, mrow, srow, tid, fl, fh, wid);
    }

    if (WORD) {
        // masked mean over chars (f32, shuffle over fh) -> NE[w2n*8+wpos]
#pragma unroll
        for (int m = 0; m < 4; ++m) {
            int cnt = 0;
#pragma unroll
            for (int c = 0; c < 16; ++c) if (ch[m * 16 + c] != 0) ++cnt;
            float inv = 1.f / (float)cnt;
#pragma unroll
            for (int i = 0; i < 2; ++i) {
                float s = 0.f;
#pragma unroll
                for (int r = 0; r < 4; ++r)
                    if (ch[m * 16 + fh * 4 + r] != 0) s += xr[m][r][i];
                s += __shfl_xor(s, 16, 64);
                s += __shfl_xor(s, 32, 64);
                if (fh == 0) {
                    int wg = blk * 4 + m;
                    size_t nrow = (size_t)w2n[wg] * 8 + wpos[wg];
                    NE[nrow * 256 + (wid * 2 + i) * 16 + fl] = s * inv;
                }
            }
        }
    } else {
        // np2-masked mean over 8 slots (pristine NE) -> out
#pragma unroll
        for (int m = 0; m < 4; ++m)
#pragma unroll
            for (int i = 0; i < 2; ++i) {
                int col = (wid * 2 + i) * 16 + fl;
                float s = 0.f, c = 0.f;
#pragma unroll
                for (int r = 0; r < 4; ++r) {
                    int row = m * 16 + fh * 4 + r;
                    float nev = NE[((size_t)blk * 64 + row) * 256 + col];
                    if (nev != 0.f) { s += xr[m][r][i]; c += 1.f; }
                }
                s += __shfl_xor(s, 16, 64);
                c += __shfl_xor(c, 16, 64);
                if ((fh & 1) == 0) {
                    int name = blk * 8 + 2 * m + (fh >> 1);
                    out[(size_t)name * 256 + col] = (c > 0.f) ? s / c : 0.f;
                }
            }
    }
}

// =======================================================================================
extern "C" void kernel_launch(void* const* d_in, const int* in_sizes, int n_in,
                              void* d_out, int out_size, void* d_ws, size_t ws_size,
                              hipStream_t stream) {
    float* out = (float*)d_out;

    const int* inputs    = (const int*)d_in[0];
    const int* w2n       = (const int*)d_in[1];
    const int* wpos      = (const int*)d_in[2];
    const float* char_emb = (const float*)d_in[3];
    const float* pos_emb  = (const float*)d_in[4];
    const float* we_Wqkv = (const float*)d_in[5];
    const float* we_Wo   = (const float*)d_in[6];
    const float* we_ln1s = (const float*)d_in[7];
    const float* we_ln1b = (const float*)d_in[8];
    const float* we_W1   = (const float*)d_in[9];
    const float* we_W2   = (const float*)d_in[10];
    const float* we_ln2s = (const float*)d_in[11];
    const float* we_ln2b = (const float*)d_in[12];
    const float* ne_Wqkv = (const float*)d_in[13];
    const float* ne_Wo   = (const float*)d_in[14];
    const float* ne_ln1s = (const float*)d_in[15];
    const float* ne_ln1b = (const float*)d_in[16];
    const float* ne_W1   = (const float*)d_in[17];
    const float* ne_W2   = (const float*)d_in[18];
    const float* ne_ln2s = (const float*)d_in[19];
    const float* ne_ln2b = (const float*)d_in[20];

    char* ws = (char*)d_ws;
    size_t off = 0;
    auto alloc = [&](size_t bytes) { void* p = ws + off; off += (bytes + 255) & ~(size_t)255; return p; };
    float* NE = (float*)alloc((size_t)16384 * 256 * 4);
    unsigned short* qkvT_we = (unsigned short*)alloc((size_t)2 * 196608 * 2);
    unsigned short* woT_we  = (unsigned short*)alloc((size_t)2 * 65536 * 2);
    unsigned short* w1T_we  = (unsigned short*)alloc((size_t)2 * 262144 * 2);
    unsigned short* w2T_we  = (unsigned short*)alloc((size_t)2 * 262144 * 2);
    unsigned short* qkvT_ne = (unsigned short*)alloc((size_t)2 * 196608 * 2);
    unsigned short* woT_ne  = (unsigned short*)alloc((size_t)2 * 65536 * 2);
    unsigned short* w1T_ne  = (unsigned short*)alloc((size_t)2 * 262144 * 2);
    unsigned short* w2T_ne  = (unsigned short*)alloc((size_t)2 * 262144 * 2);

    for (int l = 0; l < 2; ++l) {
        k_wt<<<(196608 + 255) / 256, 256, 0, stream>>>(we_Wqkv + (size_t)l * 196608, qkvT_we + (size_t)l * 196608, 256, 768);
        k_wt<<<(65536  + 255) / 256, 256, 0, stream>>>(we_Wo   + (size_t)l * 65536,  woT_we  + (size_t)l * 65536,  256, 256);
        k_wt<<<(262144 + 255) / 256, 256, 0, stream>>>(we_W1   + (size_t)l * 262144, w1T_we  + (size_t)l * 262144, 256, 1024);
        k_wt<<<(262144 + 255) / 256, 256, 0, stream>>>(we_W2   + (size_t)l * 262144, w2T_we  + (size_t)l * 262144, 1024, 256);
        k_wt<<<(196608 + 255) / 256, 256, 0, stream>>>(ne_Wqkv + (size_t)l * 196608, qkvT_ne + (size_t)l * 196608, 256, 768);
        k_wt<<<(65536  + 255) / 256, 256, 0, stream>>>(ne_Wo   + (size_t)l * 65536,  woT_ne  + (size_t)l * 65536,  256, 256);
        k_wt<<<(262144 + 255) / 256, 256, 0, stream>>>(ne_W1   + (size_t)l * 262144, w1T_ne  + (size_t)l * 262144, 256, 1024);
        k_wt<<<(262144 + 255) / 256, 256, 0, stream>>>(ne_W2   + (size_t)l * 262144, w2T_ne  + (size_t)l * 262144, 1024, 256);
    }

    (void)hipMemsetAsync(NE, 0, (size_t)16384 * 256 * 4, stream);

    k_enc64<true><<<2304, 512, 0, stream>>>(inputs, char_emb, pos_emb,
                                            qkvT_we, woT_we, w1T_we, w2T_we,
                                            we_ln1s, we_ln1b, we_ln2s, we_ln2b,
                                            w2n, wpos, NE, nullptr);

    k_enc64<false><<<256, 512, 0, stream>>>(nullptr, nullptr, nullptr,
                                            qkvT_ne, woT_ne, w1T_ne, w2T_ne,
                                            ne_ln1s, ne_ln1b, ne_ln2s, ne_ln2b,
                                            nullptr, nullptr, NE, out);
}

// Round 19
// 1535.117 us; speedup vs baseline: 1.0983x; 1.0983x over previous
//
#include <hip/hip_runtime.h>
#include <hip/hip_bf16.h>

using short8 = __attribute__((ext_vector_type(8))) short;
using f32x4  = __attribute__((ext_vector_type(4))) float;

#define DEV __device__ __forceinline__
#define LDB 264

DEV float bu(unsigned short u) { union { unsigned int i; float f; } z; z.i = (unsigned)u << 16; return z.f; }
DEV unsigned short fb(float f) { __hip_bfloat16 h = __float2bfloat16(f); return *reinterpret_cast<unsigned short*>(&h); }

DEV float gelu_f(float v) {
    float u = 0.7978845608028654f * (v + 0.044715f * v * v * v);
    u = fminf(fmaxf(u, -20.f), 20.f);
    float e = __expf(2.f * u);
    return 0.5f * v * (1.f + (e - 1.f) / (e + 1.f));
}

// ---------------- weight prep: WT[n][k] = bf16(W[k][n]) ----------------
__global__ void k_wt(const float* __restrict__ W, unsigned short* __restrict__ WT, int K, int N) {
    int i = blockIdx.x * 256 + threadIdx.x;
    if (i >= N * K) return;
    int n = i / K, k = i % K;
    WT[i] = fb(W[(size_t)k * N + n]);
}

// ---------------------------------------------------------------------------------------
// Per-wave MFMA: acc[NT][4] += A[64 rows][256](bf16 LDS, ld LDB) @ B[(nt0+i)*16+fl][ldB]^T
// A-frag: row=m*16+fl, k=fh*8+j. D: row=m*16+fh*4+r, col=(nt0+i)*16+fl  [m89-verified].
// ---------------------------------------------------------------------------------------
template<int NT, int KG>
DEV void mm64(const unsigned short* __restrict__ A, const unsigned short* __restrict__ B,
              int ldB, int koff, f32x4 acc[NT][4], int nt0, int lane)
{
    const int fl = lane & 15, fh = lane >> 4;
#pragma unroll
    for (int kg = 0; kg < KG; ++kg) {
        short8 b[NT];
#pragma unroll
        for (int i = 0; i < NT; ++i)
            b[i] = *(const short8*)(B + (size_t)((nt0 + i) * 16 + fl) * ldB + koff + kg * 32 + fh * 8);
        short8 a[4];
#pragma unroll
        for (int m = 0; m < 4; ++m)
            a[m] = *(const short8*)(A + (m * 16 + fl) * LDB + kg * 32 + fh * 8);
#pragma unroll
        for (int i = 0; i < NT; ++i)
#pragma unroll
            for (int m = 0; m < 4; ++m)
                acc[i][m] = __builtin_amdgcn_mfma_f32_16x16x32_bf16(a[m], b[i], acc[i][m], 0, 0, 0);
    }
}

template<int NT, bool GEL>
DEV void store_bf16(f32x4 acc[NT][4], unsigned short* __restrict__ D, int nt0, int lane) {
    const int fl = lane & 15, r0 = (lane >> 4) * 4;
#pragma unroll
    for (int i = 0; i < NT; ++i)
#pragma unroll
        for (int m = 0; m < 4; ++m)
#pragma unroll
            for (int r = 0; r < 4; ++r) {
                float v = acc[i][m][r];
                if (GEL) v = gelu_f(v);
                D[(m * 16 + r0 + r) * LDB + (nt0 + i) * 16 + fl] = fb(v);
            }
}

// f32 LayerNorm over register-resident xr; stats via shfl + red[64][8]; writes bf16 xb.
DEV void ln_reg(float xr[4][4][2], const float* __restrict__ s, const float* __restrict__ b,
                unsigned short* __restrict__ xb, float red[64][8],
                float* mrow, float* srow, int tid, int fl, int fh, int wid)
{
    float ps[4][4];
#pragma unroll
    for (int m = 0; m < 4; ++m)
#pragma unroll
        for (int r = 0; r < 4; ++r) {
            float v = xr[m][r][0] + xr[m][r][1];
#pragma unroll
            for (int off = 8; off >= 1; off >>= 1) v += __shfl_xor(v, off, 64);
            ps[m][r] = v;
        }
    if (fl == 0)
#pragma unroll
        for (int m = 0; m < 4; ++m)
#pragma unroll
            for (int r = 0; r < 4; ++r) red[m * 16 + fh * 4 + r][wid] = ps[m][r];
    __syncthreads();
    if (tid < 64) {
        float sum = 0.f;
#pragma unroll
        for (int j = 0; j < 8; ++j) sum += red[tid][j];
        mrow[tid] = sum * (1.f / 256.f);
    }
    __syncthreads();
#pragma unroll
    for (int m = 0; m < 4; ++m)
#pragma unroll
        for (int r = 0; r < 4; ++r) {
            float mu = mrow[m * 16 + fh * 4 + r];
            float d0 = xr[m][r][0] - mu, d1 = xr[m][r][1] - mu;
            float v = d0 * d0 + d1 * d1;
#pragma unroll
            for (int off = 8; off >= 1; off >>= 1) v += __shfl_xor(v, off, 64);
            ps[m][r] = v;
        }
    if (fl == 0)
#pragma unroll
        for (int m = 0; m < 4; ++m)
#pragma unroll
            for (int r = 0; r < 4; ++r) red[m * 16 + fh * 4 + r][wid] = ps[m][r];
    __syncthreads();
    if (tid < 64) {
        float sum = 0.f;
#pragma unroll
        for (int j = 0; j < 8; ++j) sum += red[tid][j];
        srow[tid] = rsqrtf(sum * (1.f / 256.f) + 1e-5f);
    }
    __syncthreads();
    float sc[2], bc[2];
#pragma unroll
    for (int i = 0; i < 2; ++i) { int c = (wid * 2 + i) * 16 + fl; sc[i] = s[c]; bc[i] = b[c]; }
#pragma unroll
    for (int m = 0; m < 4; ++m)
#pragma unroll
        for (int r = 0; r < 4; ++r) {
            int row = m * 16 + fh * 4 + r;
            float mu = mrow[row], rs = srow[row];
#pragma unroll
            for (int i = 0; i < 2; ++i) {
                float v = (xr[m][r][i] - mu) * rs * sc[i] + bc[i];
                xr[m][r][i] = v;
                xb[row * LDB + (wid * 2 + i) * 16 + fl] = fb(v);
            }
        }
    __syncthreads();
}

// ---------------------------------------------------------------------------------------
// Fused 2-layer encoder, M=64/block, f32 register residual, TWO LDS buffers (xb + SS)
// so 2 blocks/CU co-reside (70 KB LDS). Q/K/V time-share SS, barrier-separated.
// ---------------------------------------------------------------------------------------
template<bool WORD>
__global__ __launch_bounds__(512, 4) void k_enc64(
    const int* __restrict__ inputs,
    const float* __restrict__ char_emb, const float* __restrict__ pos_emb,
    const unsigned short* __restrict__ qkvT, const unsigned short* __restrict__ woT,
    const unsigned short* __restrict__ w1T,  const unsigned short* __restrict__ w2T,
    const float* __restrict__ ln1s, const float* __restrict__ ln1b,
    const float* __restrict__ ln2s, const float* __restrict__ ln2b,
    const int* __restrict__ w2n, const int* __restrict__ wpos,
    float* __restrict__ NE, float* __restrict__ out)
{
    constexpr int T = WORD ? 16 : 8;
    const int blk = blockIdx.x, tid = threadIdx.x;
    const int lane = tid & 63, wid = tid >> 6;
    const int fl = lane & 15, fh = lane >> 4;
    __shared__ __attribute__((aligned(16))) unsigned short xb[64 * LDB];  // bf16 A-operand
    __shared__ __attribute__((aligned(16))) unsigned short SS[64 * LDB];  // Q/K/V/o/hidden
    __shared__ float red[64][8];
    __shared__ float mrow[64], srow[64];
    __shared__ int ch[64];

    const int wl = WORD ? (tid >> 7) : (tid >> 6);
    const int hh = WORD ? ((tid >> 4) & 7) : ((tid >> 3) & 7);
    const int tt = WORD ? (tid & 15) : (tid & 7);
    const int arow = wl * T + tt;

    float xr[4][4][2];   // f32 residual stream (this thread's MFMA D-fragment cells)

    if (WORD) {
        if (tid < 64) ch[tid] = inputs[blk * 64 + tid];
        __syncthreads();
#pragma unroll
        for (int m = 0; m < 4; ++m)
#pragma unroll
            for (int r = 0; r < 4; ++r) {
                int row = m * 16 + fh * 4 + r;
#pragma unroll
                for (int i = 0; i < 2; ++i) {
                    int col = (wid * 2 + i) * 16 + fl;
                    float v = char_emb[(size_t)ch[row] * 256 + col] + pos_emb[(row & 15) * 256 + col];
                    xr[m][r][i] = v;
                    xb[row * LDB + col] = fb(v);
                }
            }
    } else {
#pragma unroll
        for (int m = 0; m < 4; ++m)
#pragma unroll
            for (int r = 0; r < 4; ++r) {
                int row = m * 16 + fh * 4 + r;
#pragma unroll
                for (int i = 0; i < 2; ++i) {
                    int col = (wid * 2 + i) * 16 + fl;
                    float v = NE[((size_t)blk * 64 + row) * 256 + col];
                    xr[m][r][i] = v;
                    xb[row * LDB + col] = fb(v);
                }
            }
    }
    __syncthreads();

    for (int l = 0; l < 2; ++l) {
        const unsigned short* wq = qkvT + (size_t)l * 196608;
        const unsigned short* wk = wq + 65536;
        const unsigned short* wv = wq + 131072;
        const unsigned short* wo = woT + (size_t)l * 65536;
        const unsigned short* w1 = w1T + (size_t)l * 262144;
        const unsigned short* w2 = w2T + (size_t)l * 262144;

        float q[32], p[T];

        // ---- Q -> SS; q -> regs ----
        { f32x4 acc[2][4] = {}; mm64<2, 8>(xb, wq, 256, 0, acc, wid * 2, lane); store_bf16<2, false>(acc, SS, wid * 2, lane); }
        __syncthreads();
#pragma unroll
        for (int db = 0; db < 4; ++db) {
            short8 qv = *(const short8*)&SS[arow * LDB + hh * 32 + db * 8];
#pragma unroll
            for (int j = 0; j < 8; ++j) q[db * 8 + j] = bu((unsigned short)qv[j]);
        }
        __syncthreads();

        // ---- K -> SS; scores + softmax -> p[] regs ----
        { f32x4 acc[2][4] = {}; mm64<2, 8>(xb, wk, 256, 0, acc, wid * 2, lane); store_bf16<2, false>(acc, SS, wid * 2, lane); }
        __syncthreads();
        {
            float mx = -1e30f;
#pragma unroll
            for (int s = 0; s < T; ++s) {
                float dot = 0.f;
#pragma unroll
                for (int db = 0; db < 4; ++db) {
                    short8 kv = *(const short8*)&SS[(wl * T + s) * LDB + hh * 32 + db * 8];
#pragma unroll
                    for (int j = 0; j < 8; ++j) dot += q[db * 8 + j] * bu((unsigned short)kv[j]);
                }
                dot *= 0.17677669529663687f;
                if (WORD && ch[wl * 16 + s] == 0) dot = -1e9f;   // key-pad mask
                p[s] = dot; mx = fmaxf(mx, dot);
            }
            float sum = 0.f;
#pragma unroll
            for (int s = 0; s < T; ++s) { p[s] = __expf(p[s] - mx); sum += p[s]; }
            float inv = 1.f / sum;
#pragma unroll
            for (int s = 0; s < T; ++s) p[s] *= inv;
        }
        __syncthreads();

        // ---- V -> SS; PV -> o regs; o -> SS own cell ----
        { f32x4 acc[2][4] = {}; mm64<2, 8>(xb, wv, 256, 0, acc, wid * 2, lane); store_bf16<2, false>(acc, SS, wid * 2, lane); }
        __syncthreads();
        {
            float o[32];
#pragma unroll
            for (int j = 0; j < 32; ++j) o[j] = 0.f;
#pragma unroll
            for (int s = 0; s < T; ++s) {
                float ps = p[s];
#pragma unroll
                for (int db = 0; db < 4; ++db) {
                    short8 vv = *(const short8*)&SS[(wl * T + s) * LDB + hh * 32 + db * 8];
#pragma unroll
                    for (int j = 0; j < 8; ++j) o[db * 8 + j] += ps * bu((unsigned short)vv[j]);
                }
            }
            __syncthreads();                       // all V reads complete
#pragma unroll
            for (int db = 0; db < 4; ++db) {
                short8 ov;
#pragma unroll
                for (int j = 0; j < 8; ++j) ov[j] = (short)fb(o[db * 8 + j]);
                *(short8*)&SS[arow * LDB + hh * 32 + db * 8] = ov;   // own cell
            }
        }
        __syncthreads();

        // ---- Wo: SS(o) @ wo ; residual add f32 regs; LN1 -> xb ----
        { f32x4 acc[2][4] = {}; mm64<2, 8>(SS, wo, 256, 0, acc, wid * 2, lane);
#pragma unroll
          for (int i = 0; i < 2; ++i)
#pragma unroll
              for (int m = 0; m < 4; ++m)
#pragma unroll
                  for (int r = 0; r < 4; ++r) xr[m][r][i] += acc[i][m][r]; }
        __syncthreads();
        ln_reg(xr, ln1s + l * 256, ln1b + l * 256, xb, red, mrow, srow, tid, fl, fh, wid);

        // ---- FF: 4 hidden chunks through SS; FF2 accumulates f32 ----
        {
            f32x4 acc2[2][4] = {};
            for (int c = 0; c < 4; ++c) {
                f32x4 acc1[2][4] = {};
                mm64<2, 8>(xb, w1 + (size_t)c * 65536, 256, 0, acc1, wid * 2, lane);
                store_bf16<2, true>(acc1, SS, wid * 2, lane);      // gelu(hidden chunk)
                __syncthreads();
                mm64<2, 8>(SS, w2, 1024, c * 256, acc2, wid * 2, lane);
                __syncthreads();
            }
#pragma unroll
            for (int i = 0; i < 2; ++i)
#pragma unroll
                for (int m = 0; m < 4; ++m)
#pragma unroll
                    for (int r = 0; r < 4; ++r) xr[m][r][i] += acc2[i][m][r];
        }
        ln_reg(xr, ln2s + l * 256, ln2b + l * 256, xb, red, mrow, srow, tid, fl, fh, wid);
    }

    if (WORD) {
        // masked mean over chars (f32, shuffle over fh) -> NE[w2n*8+wpos]
#pragma unroll
        for (int m = 0; m < 4; ++m) {
            int cnt = 0;
#pragma unroll
            for (int c = 0; c < 16; ++c) if (ch[m * 16 + c] != 0) ++cnt;
            float inv = 1.f / (float)cnt;
#pragma unroll
            for (int i = 0; i < 2; ++i) {
                float s = 0.f;
#pragma unroll
                for (int r = 0; r < 4; ++r)
                    if (ch[m * 16 + fh * 4 + r] != 0) s += xr[m][r][i];
                s += __shfl_xor(s, 16, 64);
                s += __shfl_xor(s, 32, 64);
                if (fh == 0) {
                    int wg = blk * 4 + m;
                    size_t nrow = (size_t)w2n[wg] * 8 + wpos[wg];
                    NE[nrow * 256 + (wid * 2 + i) * 16 + fl] = s * inv;
                }
            }
        }
    } else {
        // np2-masked mean over 8 slots (pristine NE) -> out
#pragma unroll
        for (int m = 0; m < 4; ++m)
#pragma unroll
            for (int i = 0; i < 2; ++i) {
                int col = (wid * 2 + i) * 16 + fl;
                float s = 0.f, c = 0.f;
#pragma unroll
                for (int r = 0; r < 4; ++r) {
                    int row = m * 16 + fh * 4 + r;
                    float nev = NE[((size_t)blk * 64 + row) * 256 + col];
                    if (nev != 0.f) { s += xr[m][r][i]; c += 1.f; }
                }
                s += __shfl_xor(s, 16, 64);
                c += __shfl_xor(c, 16, 64);
                if ((fh & 1) == 0) {
                    int name = blk * 8 + 2 * m + (fh >> 1);
                    out[(size_t)name * 256 + col] = (c > 0.f) ? s / c : 0.f;
                }
            }
    }
}

// =======================================================================================
extern "C" void kernel_launch(void* const* d_in, const int* in_sizes, int n_in,
                              void* d_out, int out_size, void* d_ws, size_t ws_size,
                              hipStream_t stream) {
    float* out = (float*)d_out;

    const int* inputs    = (const int*)d_in[0];
    const int* w2n       = (const int*)d_in[1];
    const int* wpos      = (const int*)d_in[2];
    const float* char_emb = (const float*)d_in[3];
    const float* pos_emb  = (const float*)d_in[4];
    const float* we_Wqkv = (const float*)d_in[5];
    const float* we_Wo   = (const float*)d_in[6];
    const float* we_ln1s = (const float*)d_in[7];
    const float* we_ln1b = (const float*)d_in[8];
    const float* we_W1   = (const float*)d_in[9];
    const float* we_W2   = (const float*)d_in[10];
    const float* we_ln2s = (const float*)d_in[11];
    const float* we_ln2b = (const float*)d_in[12];
    const float* ne_Wqkv = (const float*)d_in[13];
    const float* ne_Wo   = (const float*)d_in[14];
    const float* ne_ln1s = (const float*)d_in[15];
    const float* ne_ln1b = (const float*)d_in[16];
    const float* ne_W1   = (const float*)d_in[17];
    const float* ne_W2   = (const float*)d_in[18];
    const float* ne_ln2s = (const float*)d_in[19];
    const float* ne_ln2b = (const float*)d_in[20];

    char* ws = (char*)d_ws;
    size_t off = 0;
    auto alloc = [&](size_t bytes) { void* p = ws + off; off += (bytes + 255) & ~(size_t)255; return p; };
    float* NE = (float*)alloc((size_t)16384 * 256 * 4);
    unsigned short* qkvT_we = (unsigned short*)alloc((size_t)2 * 196608 * 2);
    unsigned short* woT_we  = (unsigned short*)alloc((size_t)2 * 65536 * 2);
    unsigned short* w1T_we  = (unsigned short*)alloc((size_t)2 * 262144 * 2);
    unsigned short* w2T_we  = (unsigned short*)alloc((size_t)2 * 262144 * 2);
    unsigned short* qkvT_ne = (unsigned short*)alloc((size_t)2 * 196608 * 2);
    unsigned short* woT_ne  = (unsigned short*)alloc((size_t)2 * 65536 * 2);
    unsigned short* w1T_ne  = (unsigned short*)alloc((size_t)2 * 262144 * 2);
    unsigned short* w2T_ne  = (unsigned short*)alloc((size_t)2 * 262144 * 2);

    for (int l = 0; l < 2; ++l) {
        k_wt<<<(196608 + 255) / 256, 256, 0, stream>>>(we_Wqkv + (size_t)l * 196608, qkvT_we + (size_t)l * 196608, 256, 768);
        k_wt<<<(65536  + 255) / 256, 256, 0, stream>>>(we_Wo   + (size_t)l * 65536,  woT_we  + (size_t)l * 65536,  256, 256);
        k_wt<<<(262144 + 255) / 256, 256, 0, stream>>>(we_W1   + (size_t)l * 262144, w1T_we  + (size_t)l * 262144, 256, 1024);
        k_wt<<<(262144 + 255) / 256, 256, 0, stream>>>(we_W2   + (size_t)l * 262144, w2T_we  + (size_t)l * 262144, 1024, 256);
        k_wt<<<(196608 + 255) / 256, 256, 0, stream>>>(ne_Wqkv + (size_t)l * 196608, qkvT_ne + (size_t)l * 196608, 256, 768);
        k_wt<<<(65536  + 255) / 256, 256, 0, stream>>>(ne_Wo   + (size_t)l * 65536,  woT_ne  + (size_t)l * 65536,  256, 256);
        k_wt<<<(262144 + 255) / 256, 256, 0, stream>>>(ne_W1   + (size_t)l * 262144, w1T_ne  + (size_t)l * 262144, 256, 1024);
        k_wt<<<(262144 + 255) / 256, 256, 0, stream>>>(ne_W2   + (size_t)l * 262144, w2T_ne  + (size_t)l * 262144, 1024, 256);
    }

    (void)hipMemsetAsync(NE, 0, (size_t)16384 * 256 * 4, stream);

    k_enc64<true><<<2304, 512, 0, stream>>>(inputs, char_emb, pos_emb,
                                            qkvT_we, woT_we, w1T_we, w2T_we,
                                            we_ln1s, we_ln1b, we_ln2s, we_ln2b,
                                            w2n, wpos, NE, nullptr);

    k_enc64<false><<<256, 512, 0, stream>>>(nullptr, nullptr, nullptr,
                                            qkvT_ne, woT_ne, w1T_ne, w2T_ne,
                                            ne_ln1s, ne_ln1b, ne_ln2s, ne_ln2b,
                                            nullptr, nullptr, NE, out);
}

// Round 20
// 1531.864 us; speedup vs baseline: 1.1006x; 1.0021x over previous
//
#include <hip/hip_runtime.h>
#include <hip/hip_bf16.h>

using short8 = __attribute__((ext_vector_type(8))) short;
using f32x4  = __attribute__((ext_vector_type(4))) float;

#define DEV __device__ __forceinline__
#define LDB 264

DEV float bu(unsigned short u) { union { unsigned int i; float f; } z; z.i = (unsigned)u << 16; return z.f; }
DEV unsigned short fb(float f) { __hip_bfloat16 h = __float2bfloat16(f); return *reinterpret_cast<unsigned short*>(&h); }

DEV float gelu_f(float v) {
    float u = 0.7978845608028654f * (v + 0.044715f * v * v * v);
    u = fminf(fmaxf(u, -20.f), 20.f);
    float e = __expf(2.f * u);
    return 0.5f * v * (1.f + (e - 1.f) / (e + 1.f));
}

// ---------------- weight prep: WT[n][k] = bf16(W[k][n]) ----------------
__global__ void k_wt(const float* __restrict__ W, unsigned short* __restrict__ WT, int K, int N) {
    int i = blockIdx.x * 256 + threadIdx.x;
    if (i >= N * K) return;
    int n = i / K, k = i % K;
    WT[i] = fb(W[(size_t)k * N + n]);
}

// ---------------------------------------------------------------------------------------
// Per-wave MFMA: acc[NT][4] += A[64 rows][256](bf16 LDS, ld LDB) @ B[(nt0+i)*16+fl][ldB]^T
// A-frag: row=m*16+fl, k=fh*8+j. D: row=m*16+fh*4+r, col=(nt0+i)*16+fl  [m89-verified].
// ---------------------------------------------------------------------------------------
template<int NT, int KG>
DEV void mm64(const unsigned short* __restrict__ A, const unsigned short* __restrict__ B,
              int ldB, int koff, f32x4 acc[NT][4], int nt0, int lane)
{
    const int fl = lane & 15, fh = lane >> 4;
#pragma unroll
    for (int kg = 0; kg < KG; ++kg) {
        short8 b[NT];
#pragma unroll
        for (int i = 0; i < NT; ++i)
            b[i] = *(const short8*)(B + (size_t)((nt0 + i) * 16 + fl) * ldB + koff + kg * 32 + fh * 8);
        short8 a[4];
#pragma unroll
        for (int m = 0; m < 4; ++m)
            a[m] = *(const short8*)(A + (m * 16 + fl) * LDB + kg * 32 + fh * 8);
#pragma unroll
        for (int i = 0; i < NT; ++i)
#pragma unroll
            for (int m = 0; m < 4; ++m)
                acc[i][m] = __builtin_amdgcn_mfma_f32_16x16x32_bf16(a[m], b[i], acc[i][m], 0, 0, 0);
    }
}

template<int NT, bool GEL>
DEV void store_bf16(f32x4 acc[NT][4], unsigned short* __restrict__ D, int nt0, int lane) {
    const int fl = lane & 15, r0 = (lane >> 4) * 4;
#pragma unroll
    for (int i = 0; i < NT; ++i)
#pragma unroll
        for (int m = 0; m < 4; ++m)
#pragma unroll
            for (int r = 0; r < 4; ++r) {
                float v = acc[i][m][r];
                if (GEL) v = gelu_f(v);
                D[(m * 16 + r0 + r) * LDB + (nt0 + i) * 16 + fl] = fb(v);
            }
}

// f32 LayerNorm over register-resident xr; stats via shfl + red[64][8]; writes bf16 xb.
DEV void ln_reg(float xr[4][4][2], const float* __restrict__ s, const float* __restrict__ b,
                unsigned short* __restrict__ xb, float red[64][8],
                float* mrow, float* srow, int tid, int fl, int fh, int wid)
{
    float ps[4][4];
#pragma unroll
    for (int m = 0; m < 4; ++m)
#pragma unroll
        for (int r = 0; r < 4; ++r) {
            float v = xr[m][r][0] + xr[m][r][1];
#pragma unroll
            for (int off = 8; off >= 1; off >>= 1) v += __shfl_xor(v, off, 64);
            ps[m][r] = v;
        }
    if (fl == 0)
#pragma unroll
        for (int m = 0; m < 4; ++m)
#pragma unroll
            for (int r = 0; r < 4; ++r) red[m * 16 + fh * 4 + r][wid] = ps[m][r];
    __syncthreads();
    if (tid < 64) {
        float sum = 0.f;
#pragma unroll
        for (int j = 0; j < 8; ++j) sum += red[tid][j];
        mrow[tid] = sum * (1.f / 256.f);
    }
    __syncthreads();
#pragma unroll
    for (int m = 0; m < 4; ++m)
#pragma unroll
        for (int r = 0; r < 4; ++r) {
            float mu = mrow[m * 16 + fh * 4 + r];
            float d0 = xr[m][r][0] - mu, d1 = xr[m][r][1] - mu;
            float v = d0 * d0 + d1 * d1;
#pragma unroll
            for (int off = 8; off >= 1; off >>= 1) v += __shfl_xor(v, off, 64);
            ps[m][r] = v;
        }
    if (fl == 0)
#pragma unroll
        for (int m = 0; m < 4; ++m)
#pragma unroll
            for (int r = 0; r < 4; ++r) red[m * 16 + fh * 4 + r][wid] = ps[m][r];
    __syncthreads();
    if (tid < 64) {
        float sum = 0.f;
#pragma unroll
        for (int j = 0; j < 8; ++j) sum += red[tid][j];
        srow[tid] = rsqrtf(sum * (1.f / 256.f) + 1e-5f);
    }
    __syncthreads();
    float sc[2], bc[2];
#pragma unroll
    for (int i = 0; i < 2; ++i) { int c = (wid * 2 + i) * 16 + fl; sc[i] = s[c]; bc[i] = b[c]; }
#pragma unroll
    for (int m = 0; m < 4; ++m)
#pragma unroll
        for (int r = 0; r < 4; ++r) {
            int row = m * 16 + fh * 4 + r;
            float mu = mrow[row], rs = srow[row];
#pragma unroll
            for (int i = 0; i < 2; ++i) {
                float v = (xr[m][r][i] - mu) * rs * sc[i] + bc[i];
                xr[m][r][i] = v;
                xb[row * LDB + (wid * 2 + i) * 16 + fl] = fb(v);
            }
        }
    __syncthreads();
}

// ---------------------------------------------------------------------------------------
// Fused 2-layer encoder, M=64/block, f32 register residual, TWO LDS buffers (xb + SS)
// so 2 blocks/CU co-reside (70 KB LDS). Q/K/V time-share SS, barrier-separated.
// ---------------------------------------------------------------------------------------
template<bool WORD>
__global__ __launch_bounds__(512, 4) void k_enc64(
    const int* __restrict__ inputs,
    const float* __restrict__ char_emb, const float* __restrict__ pos_emb,
    const unsigned short* __restrict__ qkvT, const unsigned short* __restrict__ woT,
    const unsigned short* __restrict__ w1T,  const unsigned short* __restrict__ w2T,
    const float* __restrict__ ln1s, const float* __restrict__ ln1b,
    const float* __restrict__ ln2s, const float* __restrict__ ln2b,
    const int* __restrict__ w2n, const int* __restrict__ wpos,
    float* __restrict__ NE, float* __restrict__ out)
{
    constexpr int T = WORD ? 16 : 8;
    const int blk = blockIdx.x, tid = threadIdx.x;
    const int lane = tid & 63, wid = tid >> 6;
    const int fl = lane & 15, fh = lane >> 4;
    __shared__ __attribute__((aligned(16))) unsigned short xb[64 * LDB];  // bf16 A-operand
    __shared__ __attribute__((aligned(16))) unsigned short SS[64 * LDB];  // Q/K/V/o/hidden
    __shared__ float red[64][8];
    __shared__ float mrow[64], srow[64];
    __shared__ int ch[64];

    const int wl = WORD ? (tid >> 7) : (tid >> 6);
    const int hh = WORD ? ((tid >> 4) & 7) : ((tid >> 3) & 7);
    const int tt = WORD ? (tid & 15) : (tid & 7);
    const int arow = wl * T + tt;

    float xr[4][4][2];   // f32 residual stream (this thread's MFMA D-fragment cells)

    if (WORD) {
        if (tid < 64) ch[tid] = inputs[blk * 64 + tid];
        __syncthreads();
#pragma unroll
        for (int m = 0; m < 4; ++m)
#pragma unroll
            for (int r = 0; r < 4; ++r) {
                int row = m * 16 + fh * 4 + r;
#pragma unroll
                for (int i = 0; i < 2; ++i) {
                    int col = (wid * 2 + i) * 16 + fl;
                    float v = char_emb[(size_t)ch[row] * 256 + col] + pos_emb[(row & 15) * 256 + col];
                    xr[m][r][i] = v;
                    xb[row * LDB + col] = fb(v);
                }
            }
    } else {
#pragma unroll
        for (int m = 0; m < 4; ++m)
#pragma unroll
            for (int r = 0; r < 4; ++r) {
                int row = m * 16 + fh * 4 + r;
#pragma unroll
                for (int i = 0; i < 2; ++i) {
                    int col = (wid * 2 + i) * 16 + fl;
                    float v = NE[((size_t)blk * 64 + row) * 256 + col];
                    xr[m][r][i] = v;
                    xb[row * LDB + col] = fb(v);
                }
            }
    }
    __syncthreads();

    for (int l = 0; l < 2; ++l) {
        const unsigned short* wq = qkvT + (size_t)l * 196608;
        const unsigned short* wk = wq + 65536;
        const unsigned short* wv = wq + 131072;
        const unsigned short* wo = woT + (size_t)l * 65536;
        const unsigned short* w1 = w1T + (size_t)l * 262144;
        const unsigned short* w2 = w2T + (size_t)l * 262144;

        float q[32], p[T];

        // ---- Q -> SS; q -> regs ----
        { f32x4 acc[2][4] = {}; mm64<2, 8>(xb, wq, 256, 0, acc, wid * 2, lane); store_bf16<2, false>(acc, SS, wid * 2, lane); }
        __syncthreads();
#pragma unroll
        for (int db = 0; db < 4; ++db) {
            short8 qv = *(const short8*)&SS[arow * LDB + hh * 32 + db * 8];
#pragma unroll
            for (int j = 0; j < 8; ++j) q[db * 8 + j] = bu((unsigned short)qv[j]);
        }
        __syncthreads();

        // ---- K -> SS; scores + softmax -> p[] regs ----
        { f32x4 acc[2][4] = {}; mm64<2, 8>(xb, wk, 256, 0, acc, wid * 2, lane); store_bf16<2, false>(acc, SS, wid * 2, lane); }
        __syncthreads();
        {
            float mx = -1e30f;
#pragma unroll
            for (int s = 0; s < T; ++s) {
                float dot = 0.f;
#pragma unroll
                for (int db = 0; db < 4; ++db) {
                    short8 kv = *(const short8*)&SS[(wl * T + s) * LDB + hh * 32 + db * 8];
#pragma unroll
                    for (int j = 0; j < 8; ++j) dot += q[db * 8 + j] * bu((unsigned short)kv[j]);
                }
                dot *= 0.17677669529663687f;
                if (WORD && ch[wl * 16 + s] == 0) dot = -1e9f;   // key-pad mask
                p[s] = dot; mx = fmaxf(mx, dot);
            }
            float sum = 0.f;
#pragma unroll
            for (int s = 0; s < T; ++s) { p[s] = __expf(p[s] - mx); sum += p[s]; }
            float inv = 1.f / sum;
#pragma unroll
            for (int s = 0; s < T; ++s) p[s] *= inv;
        }
        __syncthreads();

        // ---- V -> SS; PV -> o regs; o -> SS own cell ----
        { f32x4 acc[2][4] = {}; mm64<2, 8>(xb, wv, 256, 0, acc, wid * 2, lane); store_bf16<2, false>(acc, SS, wid * 2, lane); }
        __syncthreads();
        {
            float o[32];
#pragma unroll
            for (int j = 0; j < 32; ++j) o[j] = 0.f;
#pragma unroll
            for (int s = 0; s < T; ++s) {
                float ps = p[s];
#pragma unroll
                for (int db = 0; db < 4; ++db) {
                    short8 vv = *(const short8*)&SS[(wl * T + s) * LDB + hh * 32 + db * 8];
#pragma unroll
                    for (int j = 0; j < 8; ++j) o[db * 8 + j] += ps * bu((unsigned short)vv[j]);
                }
            }
            __syncthreads();                       // all V reads complete
#pragma unroll
            for (int db = 0; db < 4; ++db) {
                short8 ov;
#pragma unroll
                for (int j = 0; j < 8; ++j) ov[j] = (short)fb(o[db * 8 + j]);
                *(short8*)&SS[arow * LDB + hh * 32 + db * 8] = ov;   // own cell
            }
        }
        __syncthreads();

        // ---- Wo: SS(o) @ wo ; residual add f32 regs; LN1 -> xb ----
        { f32x4 acc[2][4] = {}; mm64<2, 8>(SS, wo, 256, 0, acc, wid * 2, lane);
#pragma unroll
          for (int i = 0; i < 2; ++i)
#pragma unroll
              for (int m = 0; m < 4; ++m)
#pragma unroll
                  for (int r = 0; r < 4; ++r) xr[m][r][i] += acc[i][m][r]; }
        __syncthreads();
        ln_reg(xr, ln1s + l * 256, ln1b + l * 256, xb, red, mrow, srow, tid, fl, fh, wid);

        // ---- FF: 4 hidden chunks through SS; FF2 accumulates f32 ----
        {
            f32x4 acc2[2][4] = {};
            for (int c = 0; c < 4; ++c) {
                f32x4 acc1[2][4] = {};
                mm64<2, 8>(xb, w1 + (size_t)c * 65536, 256, 0, acc1, wid * 2, lane);
                store_bf16<2, true>(acc1, SS, wid * 2, lane);      // gelu(hidden chunk)
                __syncthreads();
                mm64<2, 8>(SS, w2, 1024, c * 256, acc2, wid * 2, lane);
                __syncthreads();
            }
#pragma unroll
            for (int i = 0; i < 2; ++i)
#pragma unroll
                for (int m = 0; m < 4; ++m)
#pragma unroll
                    for (int r = 0; r < 4; ++r) xr[m][r][i] += acc2[i][m][r];
        }
        ln_reg(xr, ln2s + l * 256, ln2b + l * 256, xb, red, mrow, srow, tid, fl, fh, wid);
    }

    if (WORD) {
        // masked mean over chars (f32, shuffle over fh) -> NE[w2n*8+wpos]
#pragma unroll
        for (int m = 0; m < 4; ++m) {
            int cnt = 0;
#pragma unroll
            for (int c = 0; c < 16; ++c) if (ch[m * 16 + c] != 0) ++cnt;
            float inv = 1.f / (float)cnt;
#pragma unroll
            for (int i = 0; i < 2; ++i) {
                float s = 0.f;
#pragma unroll
                for (int r = 0; r < 4; ++r)
                    if (ch[m * 16 + fh * 4 + r] != 0) s += xr[m][r][i];
                s += __shfl_xor(s, 16, 64);
                s += __shfl_xor(s, 32, 64);
                if (fh == 0) {
                    int wg = blk * 4 + m;
                    size_t nrow = (size_t)w2n[wg] * 8 + wpos[wg];
                    NE[nrow * 256 + (wid * 2 + i) * 16 + fl] = s * inv;
                }
            }
        }
    } else {
        // np2-masked mean over 8 slots (pristine NE) -> out
#pragma unroll
        for (int m = 0; m < 4; ++m)
#pragma unroll
            for (int i = 0; i < 2; ++i) {
                int col = (wid * 2 + i) * 16 + fl;
                float s = 0.f, c = 0.f;
#pragma unroll
                for (int r = 0; r < 4; ++r) {
                    int row = m * 16 + fh * 4 + r;
                    float nev = NE[((size_t)blk * 64 + row) * 256 + col];
                    if (nev != 0.f) { s += xr[m][r][i]; c += 1.f; }
                }
                s += __shfl_xor(s, 16, 64);
                c += __shfl_xor(c, 16, 64);
                if ((fh & 1) == 0) {
                    int name = blk * 8 + 2 * m + (fh >> 1);
                    out[(size_t)name * 256 + col] = (c > 0.f) ? s / c : 0.f;
                }
            }
    }
}

// =======================================================================================
extern "C" void kernel_launch(void* const* d_in, const int* in_sizes, int n_in,
                              void* d_out, int out_size, void* d_ws, size_t ws_size,
                              hipStream_t stream) {
    float* out = (float*)d_out;

    const int* inputs    = (const int*)d_in[0];
    const int* w2n       = (const int*)d_in[1];
    const int* wpos      = (const int*)d_in[2];
    const float* char_emb = (const float*)d_in[3];
    const float* pos_emb  = (const float*)d_in[4];
    const float* we_Wqkv = (const float*)d_in[5];
    const float* we_Wo   = (const float*)d_in[6];
    const float* we_ln1s = (const float*)d_in[7];
    const float* we_ln1b = (const float*)d_in[8];
    const float* we_W1   = (const float*)d_in[9];
    const float* we_W2   = (const float*)d_in[10];
    const float* we_ln2s = (const float*)d_in[11];
    const float* we_ln2b = (const float*)d_in[12];
    const float* ne_Wqkv = (const float*)d_in[13];
    const float* ne_Wo   = (const float*)d_in[14];
    const float* ne_ln1s = (const float*)d_in[15];
    const float* ne_ln1b = (const float*)d_in[16];
    const float* ne_W1   = (const float*)d_in[17];
    const float* ne_W2   = (const float*)d_in[18];
    const float* ne_ln2s = (const float*)d_in[19];
    const float* ne_ln2b = (const float*)d_in[20];

    char* ws = (char*)d_ws;
    size_t off = 0;
    auto alloc = [&](size_t bytes) { void* p = ws + off; off += (bytes + 255) & ~(size_t)255; return p; };
    float* NE = (float*)alloc((size_t)16384 * 256 * 4);
    unsigned short* qkvT_we = (unsigned short*)alloc((size_t)2 * 196608 * 2);
    unsigned short* woT_we  = (unsigned short*)alloc((size_t)2 * 65536 * 2);
    unsigned short* w1T_we  = (unsigned short*)alloc((size_t)2 * 262144 * 2);
    unsigned short* w2T_we  = (unsigned short*)alloc((size_t)2 * 262144 * 2);
    unsigned short* qkvT_ne = (unsigned short*)alloc((size_t)2 * 196608 * 2);
    unsigned short* woT_ne  = (unsigned short*)alloc((size_t)2 * 65536 * 2);
    unsigned short* w1T_ne  = (unsigned short*)alloc((size_t)2 * 262144 * 2);
    unsigned short* w2T_ne  = (unsigned short*)alloc((size_t)2 * 262144 * 2);

    for (int l = 0; l < 2; ++l) {
        k_wt<<<(196608 + 255) / 256, 256, 0, stream>>>(we_Wqkv + (size_t)l * 196608, qkvT_we + (size_t)l * 196608, 256, 768);
        k_wt<<<(65536  + 255) / 256, 256, 0, stream>>>(we_Wo   + (size_t)l * 65536,  woT_we  + (size_t)l * 65536,  256, 256);
        k_wt<<<(262144 + 255) / 256, 256, 0, stream>>>(we_W1   + (size_t)l * 262144, w1T_we  + (size_t)l * 262144, 256, 1024);
        k_wt<<<(262144 + 255) / 256, 256, 0, stream>>>(we_W2   + (size_t)l * 262144, w2T_we  + (size_t)l * 262144, 1024, 256);
        k_wt<<<(196608 + 255) / 256, 256, 0, stream>>>(ne_Wqkv + (size_t)l * 196608, qkvT_ne + (size_t)l * 196608, 256, 768);
        k_wt<<<(65536  + 255) / 256, 256, 0, stream>>>(ne_Wo   + (size_t)l * 65536,  woT_ne  + (size_t)l * 65536,  256, 256);
        k_wt<<<(262144 + 255) / 256, 256, 0, stream>>>(ne_W1   + (size_t)l * 262144, w1T_ne  + (size_t)l * 262144, 256, 1024);
        k_wt<<<(262144 + 255) / 256, 256, 0, stream>>>(ne_W2   + (size_t)l * 262144, w2T_ne  + (size_t)l * 262144, 1024, 256);
    }

    (void)hipMemsetAsync(NE, 0, (size_t)16384 * 256 * 4, stream);

    k_enc64<true><<<2304, 512, 0, stream>>>(inputs, char_emb, pos_emb,
                                            qkvT_we, woT_we, w1T_we, w2T_we,
                                            we_ln1s, we_ln1b, we_ln2s, we_ln2b,
                                            w2n, wpos, NE, nullptr);

    k_enc64<false><<<256, 512, 0, stream>>>(nullptr, nullptr, nullptr,
                                            qkvT_ne, woT_ne, w1T_ne, w2T_ne,
                                            ne_ln1s, ne_ln1b, ne_ln2s, ne_ln2b,
                                            nullptr, nullptr, NE, out);
}

// Round 21
// 1454.569 us; speedup vs baseline: 1.1591x; 1.0531x over previous
//
#include <hip/hip_runtime.h>
#include <hip/hip_bf16.h>

using short8 = __attribute__((ext_vector_type(8))) short;
using f32x4  = __attribute__((ext_vector_type(4))) float;

#define DEV __device__ __forceinline__
#define LDB 264

DEV float bu(unsigned short u) { union { unsigned int i; float f; } z; z.i = (unsigned)u << 16; return z.f; }
DEV unsigned short fb(float f) { __hip_bfloat16 h = __float2bfloat16(f); return *reinterpret_cast<unsigned short*>(&h); }

DEV float gelu_f(float v) {
    float u = 0.7978845608028654f * (v + 0.044715f * v * v * v);
    u = fminf(fmaxf(u, -20.f), 20.f);
    float e = __expf(2.f * u);
    return 0.5f * v * (1.f + (e - 1.f) / (e + 1.f));
}

// ---------------- weight prep: WT[n][k] = bf16(W[k][n]) ----------------
__global__ void k_wt(const float* __restrict__ W, unsigned short* __restrict__ WT, int K, int N) {
    int i = blockIdx.x * 256 + threadIdx.x;
    if (i >= N * K) return;
    int n = i / K, k = i % K;
    WT[i] = fb(W[(size_t)k * N + n]);
}

// ---------------------------------------------------------------------------------------
// Per-wave MFMA: acc[NT][4] += A[64 rows][256](bf16 LDS, ld LDB) @ B[(nt0+i)*16+fl][ldB]^T
// A-frag: row=m*16+fl, k=fh*8+j. D: row=m*16+fh*4+r, col=(nt0+i)*16+fl  [m89-verified].
// ---------------------------------------------------------------------------------------
template<int NT, int KG>
DEV void mm64(const unsigned short* __restrict__ A, const unsigned short* __restrict__ B,
              int ldB, int koff, f32x4 acc[NT][4], int nt0, int lane)
{
    const int fl = lane & 15, fh = lane >> 4;
#pragma unroll
    for (int kg = 0; kg < KG; ++kg) {
        short8 b[NT];
#pragma unroll
        for (int i = 0; i < NT; ++i)
            b[i] = *(const short8*)(B + (size_t)((nt0 + i) * 16 + fl) * ldB + koff + kg * 32 + fh * 8);
        short8 a[4];
#pragma unroll
        for (int m = 0; m < 4; ++m)
            a[m] = *(const short8*)(A + (m * 16 + fl) * LDB + kg * 32 + fh * 8);
#pragma unroll
        for (int i = 0; i < NT; ++i)
#pragma unroll
            for (int m = 0; m < 4; ++m)
                acc[i][m] = __builtin_amdgcn_mfma_f32_16x16x32_bf16(a[m], b[i], acc[i][m], 0, 0, 0);
    }
}

template<int NT, bool GEL>
DEV void store_bf16(f32x4 acc[NT][4], unsigned short* __restrict__ D, int nt0, int lane) {
    const int fl = lane & 15, r0 = (lane >> 4) * 4;
#pragma unroll
    for (int i = 0; i < NT; ++i)
#pragma unroll
        for (int m = 0; m < 4; ++m)
#pragma unroll
            for (int r = 0; r < 4; ++r) {
                float v = acc[i][m][r];
                if (GEL) v = gelu_f(v);
                D[(m * 16 + r0 + r) * LDB + (nt0 + i) * 16 + fl] = fb(v);
            }
}

// f32 LayerNorm over register-resident xr; stats via shfl + red[64][8]; writes bf16 xb.
DEV void ln_reg(float xr[4][4][2], const float* __restrict__ s, const float* __restrict__ b,
                unsigned short* __restrict__ xb, float red[64][8],
                float* mrow, float* srow, int tid, int fl, int fh, int wid)
{
    float ps[4][4];
#pragma unroll
    for (int m = 0; m < 4; ++m)
#pragma unroll
        for (int r = 0; r < 4; ++r) {
            float v = xr[m][r][0] + xr[m][r][1];
#pragma unroll
            for (int off = 8; off >= 1; off >>= 1) v += __shfl_xor(v, off, 64);
            ps[m][r] = v;
        }
    if (fl == 0)
#pragma unroll
        for (int m = 0; m < 4; ++m)
#pragma unroll
            for (int r = 0; r < 4; ++r) red[m * 16 + fh * 4 + r][wid] = ps[m][r];
    __syncthreads();
    if (tid < 64) {
        float sum = 0.f;
#pragma unroll
        for (int j = 0; j < 8; ++j) sum += red[tid][j];
        mrow[tid] = sum * (1.f / 256.f);
    }
    __syncthreads();
#pragma unroll
    for (int m = 0; m < 4; ++m)
#pragma unroll
        for (int r = 0; r < 4; ++r) {
            float mu = mrow[m * 16 + fh * 4 + r];
            float d0 = xr[m][r][0] - mu, d1 = xr[m][r][1] - mu;
            float v = d0 * d0 + d1 * d1;
#pragma unroll
            for (int off = 8; off >= 1; off >>= 1) v += __shfl_xor(v, off, 64);
            ps[m][r] = v;
        }
    if (fl == 0)
#pragma unroll
        for (int m = 0; m < 4; ++m)
#pragma unroll
            for (int r = 0; r < 4; ++r) red[m * 16 + fh * 4 + r][wid] = ps[m][r];
    __syncthreads();
    if (tid < 64) {
        float sum = 0.f;
#pragma unroll
        for (int j = 0; j < 8; ++j) sum += red[tid][j];
        srow[tid] = rsqrtf(sum * (1.f / 256.f) + 1e-5f);
    }
    __syncthreads();
    float sc[2], bc[2];
#pragma unroll
    for (int i = 0; i < 2; ++i) { int c = (wid * 2 + i) * 16 + fl; sc[i] = s[c]; bc[i] = b[c]; }
#pragma unroll
    for (int m = 0; m < 4; ++m)
#pragma unroll
        for (int r = 0; r < 4; ++r) {
            int row = m * 16 + fh * 4 + r;
            float mu = mrow[row], rs = srow[row];
#pragma unroll
            for (int i = 0; i < 2; ++i) {
                float v = (xr[m][r][i] - mu) * rs * sc[i] + bc[i];
                xr[m][r][i] = v;
                xb[row * LDB + (wid * 2 + i) * 16 + fl] = fb(v);
            }
        }
    __syncthreads();
}

// ---------------------------------------------------------------------------------------
// Fused 2-layer encoder, M=64/block, f32 register residual, TWO LDS buffers (xb + SS),
// 2 blocks/CU. FF2 folds into xr per chunk (no persistent acc2 -> fits 128 VGPR).
// ---------------------------------------------------------------------------------------
template<bool WORD>
__global__ __launch_bounds__(512, 4) void k_enc64(
    const int* __restrict__ inputs,
    const float* __restrict__ char_emb, const float* __restrict__ pos_emb,
    const unsigned short* __restrict__ qkvT, const unsigned short* __restrict__ woT,
    const unsigned short* __restrict__ w1T,  const unsigned short* __restrict__ w2T,
    const float* __restrict__ ln1s, const float* __restrict__ ln1b,
    const float* __restrict__ ln2s, const float* __restrict__ ln2b,
    const int* __restrict__ w2n, const int* __restrict__ wpos,
    float* __restrict__ NE, float* __restrict__ out)
{
    constexpr int T = WORD ? 16 : 8;
    const int blk = blockIdx.x, tid = threadIdx.x;
    const int lane = tid & 63, wid = tid >> 6;
    const int fl = lane & 15, fh = lane >> 4;
    __shared__ __attribute__((aligned(16))) unsigned short xb[64 * LDB];  // bf16 A-operand
    __shared__ __attribute__((aligned(16))) unsigned short SS[64 * LDB];  // Q/K/V/o/hidden
    __shared__ float red[64][8];
    __shared__ float mrow[64], srow[64];
    __shared__ int ch[64];

    const int wl = WORD ? (tid >> 7) : (tid >> 6);
    const int hh = WORD ? ((tid >> 4) & 7) : ((tid >> 3) & 7);
    const int tt = WORD ? (tid & 15) : (tid & 7);
    const int arow = wl * T + tt;

    float xr[4][4][2];   // f32 residual stream (this thread's MFMA D-fragment cells)

    if (WORD) {
        if (tid < 64) ch[tid] = inputs[blk * 64 + tid];
        __syncthreads();
#pragma unroll
        for (int m = 0; m < 4; ++m)
#pragma unroll
            for (int r = 0; r < 4; ++r) {
                int row = m * 16 + fh * 4 + r;
#pragma unroll
                for (int i = 0; i < 2; ++i) {
                    int col = (wid * 2 + i) * 16 + fl;
                    float v = char_emb[(size_t)ch[row] * 256 + col] + pos_emb[(row & 15) * 256 + col];
                    xr[m][r][i] = v;
                    xb[row * LDB + col] = fb(v);
                }
            }
    } else {
#pragma unroll
        for (int m = 0; m < 4; ++m)
#pragma unroll
            for (int r = 0; r < 4; ++r) {
                int row = m * 16 + fh * 4 + r;
#pragma unroll
                for (int i = 0; i < 2; ++i) {
                    int col = (wid * 2 + i) * 16 + fl;
                    float v = NE[((size_t)blk * 64 + row) * 256 + col];
                    xr[m][r][i] = v;
                    xb[row * LDB + col] = fb(v);
                }
            }
    }
    __syncthreads();

    for (int l = 0; l < 2; ++l) {
        const unsigned short* wq = qkvT + (size_t)l * 196608;
        const unsigned short* wk = wq + 65536;
        const unsigned short* wv = wq + 131072;
        const unsigned short* wo = woT + (size_t)l * 65536;
        const unsigned short* w1 = w1T + (size_t)l * 262144;
        const unsigned short* w2 = w2T + (size_t)l * 262144;

        float q[32], p[T];

        // ---- Q -> SS; q -> regs ----
        { f32x4 acc[2][4] = {}; mm64<2, 8>(xb, wq, 256, 0, acc, wid * 2, lane); store_bf16<2, false>(acc, SS, wid * 2, lane); }
        __syncthreads();
#pragma unroll
        for (int db = 0; db < 4; ++db) {
            short8 qv = *(const short8*)&SS[arow * LDB + hh * 32 + db * 8];
#pragma unroll
            for (int j = 0; j < 8; ++j) q[db * 8 + j] = bu((unsigned short)qv[j]);
        }
        __syncthreads();

        // ---- K -> SS; scores + softmax -> p[] regs ----
        { f32x4 acc[2][4] = {}; mm64<2, 8>(xb, wk, 256, 0, acc, wid * 2, lane); store_bf16<2, false>(acc, SS, wid * 2, lane); }
        __syncthreads();
        {
            float mx = -1e30f;
#pragma unroll
            for (int s = 0; s < T; ++s) {
                float dot = 0.f;
#pragma unroll
                for (int db = 0; db < 4; ++db) {
                    short8 kv = *(const short8*)&SS[(wl * T + s) * LDB + hh * 32 + db * 8];
#pragma unroll
                    for (int j = 0; j < 8; ++j) dot += q[db * 8 + j] * bu((unsigned short)kv[j]);
                }
                dot *= 0.17677669529663687f;
                if (WORD && ch[wl * 16 + s] == 0) dot = -1e9f;   // key-pad mask
                p[s] = dot; mx = fmaxf(mx, dot);
            }
            float sum = 0.f;
#pragma unroll
            for (int s = 0; s < T; ++s) { p[s] = __expf(p[s] - mx); sum += p[s]; }
            float inv = 1.f / sum;
#pragma unroll
            for (int s = 0; s < T; ++s) p[s] *= inv;
        }
        __syncthreads();

        // ---- V -> SS; PV -> o regs; o -> SS own cell ----
        { f32x4 acc[2][4] = {}; mm64<2, 8>(xb, wv, 256, 0, acc, wid * 2, lane); store_bf16<2, false>(acc, SS, wid * 2, lane); }
        __syncthreads();
        {
            float o[32];
#pragma unroll
            for (int j = 0; j < 32; ++j) o[j] = 0.f;
#pragma unroll
            for (int s = 0; s < T; ++s) {
                float ps = p[s];
#pragma unroll
                for (int db = 0; db < 4; ++db) {
                    short8 vv = *(const short8*)&SS[(wl * T + s) * LDB + hh * 32 + db * 8];
#pragma unroll
                    for (int j = 0; j < 8; ++j) o[db * 8 + j] += ps * bu((unsigned short)vv[j]);
                }
            }
            __syncthreads();                       // all V reads complete
#pragma unroll
            for (int db = 0; db < 4; ++db) {
                short8 ov;
#pragma unroll
                for (int j = 0; j < 8; ++j) ov[j] = (short)fb(o[db * 8 + j]);
                *(short8*)&SS[arow * LDB + hh * 32 + db * 8] = ov;   // own cell
            }
        }
        __syncthreads();

        // ---- Wo: SS(o) @ wo ; residual add f32 regs; LN1 -> xb ----
        { f32x4 acc[2][4] = {}; mm64<2, 8>(SS, wo, 256, 0, acc, wid * 2, lane);
#pragma unroll
          for (int i = 0; i < 2; ++i)
#pragma unroll
              for (int m = 0; m < 4; ++m)
#pragma unroll
                  for (int r = 0; r < 4; ++r) xr[m][r][i] += acc[i][m][r]; }
        __syncthreads();
        ln_reg(xr, ln1s + l * 256, ln1b + l * 256, xb, red, mrow, srow, tid, fl, fh, wid);

        // ---- FF: 4 hidden chunks through SS; FF2 folds into xr per chunk ----
        for (int c = 0; c < 4; ++c) {
            {
                f32x4 acc1[2][4] = {};
                mm64<2, 8>(xb, w1 + (size_t)c * 65536, 256, 0, acc1, wid * 2, lane);
                store_bf16<2, true>(acc1, SS, wid * 2, lane);      // gelu(hidden chunk)
            }
            __syncthreads();
            {
                f32x4 acc2[2][4] = {};
                mm64<2, 8>(SS, w2, 1024, c * 256, acc2, wid * 2, lane);
#pragma unroll
                for (int i = 0; i < 2; ++i)
#pragma unroll
                    for (int m = 0; m < 4; ++m)
#pragma unroll
                        for (int r = 0; r < 4; ++r) xr[m][r][i] += acc2[i][m][r];
            }
            __syncthreads();
        }
        ln_reg(xr, ln2s + l * 256, ln2b + l * 256, xb, red, mrow, srow, tid, fl, fh, wid);
    }

    if (WORD) {
        // masked mean over chars (f32, shuffle over fh) -> NE[w2n*8+wpos]
#pragma unroll
        for (int m = 0; m < 4; ++m) {
            int cnt = 0;
#pragma unroll
            for (int c = 0; c < 16; ++c) if (ch[m * 16 + c] != 0) ++cnt;
            float inv = 1.f / (float)cnt;
#pragma unroll
            for (int i = 0; i < 2; ++i) {
                float s = 0.f;
#pragma unroll
                for (int r = 0; r < 4; ++r)
                    if (ch[m * 16 + fh * 4 + r] != 0) s += xr[m][r][i];
                s += __shfl_xor(s, 16, 64);
                s += __shfl_xor(s, 32, 64);
                if (fh == 0) {
                    int wg = blk * 4 + m;
                    size_t nrow = (size_t)w2n[wg] * 8 + wpos[wg];
                    NE[nrow * 256 + (wid * 2 + i) * 16 + fl] = s * inv;
                }
            }
        }
    } else {
        // np2-masked mean over 8 slots (pristine NE) -> out
#pragma unroll
        for (int m = 0; m < 4; ++m)
#pragma unroll
            for (int i = 0; i < 2; ++i) {
                int col = (wid * 2 + i) * 16 + fl;
                float s = 0.f, c = 0.f;
#pragma unroll
                for (int r = 0; r < 4; ++r) {
                    int row = m * 16 + fh * 4 + r;
                    float nev = NE[((size_t)blk * 64 + row) * 256 + col];
                    if (nev != 0.f) { s += xr[m][r][i]; c += 1.f; }
                }
                s += __shfl_xor(s, 16, 64);
                c += __shfl_xor(c, 16, 64);
                if ((fh & 1) == 0) {
                    int name = blk * 8 + 2 * m + (fh >> 1);
                    out[(size_t)name * 256 + col] = (c > 0.f) ? s / c : 0.f;
                }
            }
    }
}

// =======================================================================================
extern "C" void kernel_launch(void* const* d_in, const int* in_sizes, int n_in,
                              void* d_out, int out_size, void* d_ws, size_t ws_size,
                              hipStream_t stream) {
    float* out = (float*)d_out;

    const int* inputs    = (const int*)d_in[0];
    const int* w2n       = (const int*)d_in[1];
    const int* wpos      = (const int*)d_in[2];
    const float* char_emb = (const float*)d_in[3];
    const float* pos_emb  = (const float*)d_in[4];
    const float* we_Wqkv = (const float*)d_in[5];
    const float* we_Wo   = (const float*)d_in[6];
    const float* we_ln1s = (const float*)d_in[7];
    const float* we_ln1b = (const float*)d_in[8];
    const float* we_W1   = (const float*)d_in[9];
    const float* we_W2   = (const float*)d_in[10];
    const float* we_ln2s = (const float*)d_in[11];
    const float* we_ln2b = (const float*)d_in[12];
    const float* ne_Wqkv = (const float*)d_in[13];
    const float* ne_Wo   = (const float*)d_in[14];
    const float* ne_ln1s = (const float*)d_in[15];
    const float* ne_ln1b = (const float*)d_in[16];
    const float* ne_W1   = (const float*)d_in[17];
    const float* ne_W2   = (const float*)d_in[18];
    const float* ne_ln2s = (const float*)d_in[19];
    const float* ne_ln2b = (const float*)d_in[20];

    char* ws = (char*)d_ws;
    size_t off = 0;
    auto alloc = [&](size_t bytes) { void* p = ws + off; off += (bytes + 255) & ~(size_t)255; return p; };
    float* NE = (float*)alloc((size_t)16384 * 256 * 4);
    unsigned short* qkvT_we = (unsigned short*)alloc((size_t)2 * 196608 * 2);
    unsigned short* woT_we  = (unsigned short*)alloc((size_t)2 * 65536 * 2);
    unsigned short* w1T_we  = (unsigned short*)alloc((size_t)2 * 262144 * 2);
    unsigned short* w2T_we  = (unsigned short*)alloc((size_t)2 * 262144 * 2);
    unsigned short* qkvT_ne = (unsigned short*)alloc((size_t)2 * 196608 * 2);
    unsigned short* woT_ne  = (unsigned short*)alloc((size_t)2 * 65536 * 2);
    unsigned short* w1T_ne  = (unsigned short*)alloc((size_t)2 * 262144 * 2);
    unsigned short* w2T_ne  = (unsigned short*)alloc((size_t)2 * 262144 * 2);

    for (int l = 0; l < 2; ++l) {
        k_wt<<<(196608 + 255) / 256, 256, 0, stream>>>(we_Wqkv + (size_t)l * 196608, qkvT_we + (size_t)l * 196608, 256, 768);
        k_wt<<<(65536  + 255) / 256, 256, 0, stream>>>(we_Wo   + (size_t)l * 65536,  woT_we  + (size_t)l * 65536,  256, 256);
        k_wt<<<(262144 + 255) / 256, 256, 0, stream>>>(we_W1   + (size_t)l * 262144, w1T_we  + (size_t)l * 262144, 256, 1024);
        k_wt<<<(262144 + 255) / 256, 256, 0, stream>>>(we_W2   + (size_t)l * 262144, w2T_we  + (size_t)l * 262144, 1024, 256);
        k_wt<<<(196608 + 255) / 256, 256, 0, stream>>>(ne_Wqkv + (size_t)l * 196608, qkvT_ne + (size_t)l * 196608, 256, 768);
        k_wt<<<(65536  + 255) / 256, 256, 0, stream>>>(ne_Wo   + (size_t)l * 65536,  woT_ne  + (size_t)l * 65536,  256, 256);
        k_wt<<<(262144 + 255) / 256, 256, 0, stream>>>(ne_W1   + (size_t)l * 262144, w1T_ne  + (size_t)l * 262144, 256, 1024);
        k_wt<<<(262144 + 255) / 256, 256, 0, stream>>>(ne_W2   + (size_t)l * 262144, w2T_ne  + (size_t)l * 262144, 1024, 256);
    }

    (void)hipMemsetAsync(NE, 0, (size_t)16384 * 256 * 4, stream);

    k_enc64<true><<<2304, 512, 0, stream>>>(inputs, char_emb, pos_emb,
                                            qkvT_we, woT_we, w1T_we, w2T_we,
                                            we_ln1s, we_ln1b, we_ln2s, we_ln2b,
                                            w2n, wpos, NE, nullptr);

    k_enc64<false><<<256, 512, 0, stream>>>(nullptr, nullptr, nullptr,
                                            qkvT_ne, woT_ne, w1T_ne, w2T_ne,
                                            ne_ln1s, ne_ln1b, ne_ln2s, ne_ln2b,
                                            nullptr, nullptr, NE, out);
}

// Round 22
// 1443.114 us; speedup vs baseline: 1.1683x; 1.0079x over previous
//
#include <hip/hip_runtime.h>
#include <hip/hip_bf16.h>

using short8 = __attribute__((ext_vector_type(8))) short;
using f32x4  = __attribute__((ext_vector_type(4))) float;

#define DEV __device__ __forceinline__
#define LDB 264

DEV float bu(unsigned short u) { union { unsigned int i; float f; } z; z.i = (unsigned)u << 16; return z.f; }
DEV unsigned short fb(float f) { __hip_bfloat16 h = __float2bfloat16(f); return *reinterpret_cast<unsigned short*>(&h); }

DEV float gelu_f(float v) {
    float u = 0.7978845608028654f * (v + 0.044715f * v * v * v);
    u = fminf(fmaxf(u, -20.f), 20.f);
    float e = __expf(2.f * u);
    return 0.5f * v * (1.f + (e - 1.f) / (e + 1.f));
}

// ---------------- weight prep: WT[n][k] = bf16(W[k][n]) ----------------
__global__ void k_wt(const float* __restrict__ W, unsigned short* __restrict__ WT, int K, int N) {
    int i = blockIdx.x * 256 + threadIdx.x;
    if (i >= N * K) return;
    int n = i / K, k = i % K;
    WT[i] = fb(W[(size_t)k * N + n]);
}

// ---------------------------------------------------------------------------------------
// Per-wave MFMA: acc[NT][4] += A[64 rows][256](bf16 LDS, ld LDB) @ B[(nt0+i)*16+fl][ldB]^T
// A-frag: row=m*16+fl, k=fh*8+j. D: row=m*16+fh*4+r, col=(nt0+i)*16+fl  [m89-verified].
// acc is C-in AND C-out -> passing the residual stream here fuses the residual add.
// ---------------------------------------------------------------------------------------
template<int NT, int KG>
DEV void mm64(const unsigned short* __restrict__ A, const unsigned short* __restrict__ B,
              int ldB, int koff, f32x4 acc[NT][4], int nt0, int lane)
{
    const int fl = lane & 15, fh = lane >> 4;
#pragma unroll
    for (int kg = 0; kg < KG; ++kg) {
        short8 b[NT];
#pragma unroll
        for (int i = 0; i < NT; ++i)
            b[i] = *(const short8*)(B + (size_t)((nt0 + i) * 16 + fl) * ldB + koff + kg * 32 + fh * 8);
        short8 a[4];
#pragma unroll
        for (int m = 0; m < 4; ++m)
            a[m] = *(const short8*)(A + (m * 16 + fl) * LDB + kg * 32 + fh * 8);
#pragma unroll
        for (int i = 0; i < NT; ++i)
#pragma unroll
            for (int m = 0; m < 4; ++m)
                acc[i][m] = __builtin_amdgcn_mfma_f32_16x16x32_bf16(a[m], b[i], acc[i][m], 0, 0, 0);
    }
}

template<int NT, bool GEL>
DEV void store_bf16(f32x4 acc[NT][4], unsigned short* __restrict__ D, int nt0, int lane) {
    const int fl = lane & 15, r0 = (lane >> 4) * 4;
#pragma unroll
    for (int i = 0; i < NT; ++i)
#pragma unroll
        for (int m = 0; m < 4; ++m)
#pragma unroll
            for (int r = 0; r < 4; ++r) {
                float v = acc[i][m][r];
                if (GEL) v = gelu_f(v);
                D[(m * 16 + r0 + r) * LDB + (nt0 + i) * 16 + fl] = fb(v);
            }
}

// f32 LayerNorm over the register-resident residual xr[2][4] (f32x4, acc layout);
// stats via shfl + red[64][8]; writes normalized f32 back to xr and bf16 to xb.
DEV void ln_reg(f32x4 xr[2][4], const float* __restrict__ s, const float* __restrict__ b,
                unsigned short* __restrict__ xb, float red[64][8],
                float* mrow, float* srow, int tid, int fl, int fh, int wid)
{
    float ps[4][4];
#pragma unroll
    for (int m = 0; m < 4; ++m)
#pragma unroll
        for (int r = 0; r < 4; ++r) {
            float v = xr[0][m][r] + xr[1][m][r];
#pragma unroll
            for (int off = 8; off >= 1; off >>= 1) v += __shfl_xor(v, off, 64);
            ps[m][r] = v;
        }
    if (fl == 0)
#pragma unroll
        for (int m = 0; m < 4; ++m)
#pragma unroll
            for (int r = 0; r < 4; ++r) red[m * 16 + fh * 4 + r][wid] = ps[m][r];
    __syncthreads();
    if (tid < 64) {
        float sum = 0.f;
#pragma unroll
        for (int j = 0; j < 8; ++j) sum += red[tid][j];
        mrow[tid] = sum * (1.f / 256.f);
    }
    __syncthreads();
#pragma unroll
    for (int m = 0; m < 4; ++m)
#pragma unroll
        for (int r = 0; r < 4; ++r) {
            float mu = mrow[m * 16 + fh * 4 + r];
            float d0 = xr[0][m][r] - mu, d1 = xr[1][m][r] - mu;
            float v = d0 * d0 + d1 * d1;
#pragma unroll
            for (int off = 8; off >= 1; off >>= 1) v += __shfl_xor(v, off, 64);
            ps[m][r] = v;
        }
    if (fl == 0)
#pragma unroll
        for (int m = 0; m < 4; ++m)
#pragma unroll
            for (int r = 0; r < 4; ++r) red[m * 16 + fh * 4 + r][wid] = ps[m][r];
    __syncthreads();
    if (tid < 64) {
        float sum = 0.f;
#pragma unroll
        for (int j = 0; j < 8; ++j) sum += red[tid][j];
        srow[tid] = rsqrtf(sum * (1.f / 256.f) + 1e-5f);
    }
    __syncthreads();
    float sc[2], bc[2];
#pragma unroll
    for (int i = 0; i < 2; ++i) { int c = (wid * 2 + i) * 16 + fl; sc[i] = s[c]; bc[i] = b[c]; }
#pragma unroll
    for (int m = 0; m < 4; ++m)
#pragma unroll
        for (int r = 0; r < 4; ++r) {
            int row = m * 16 + fh * 4 + r;
            float mu = mrow[row], rs = srow[row];
#pragma unroll
            for (int i = 0; i < 2; ++i) {
                float v = (xr[i][m][r] - mu) * rs * sc[i] + bc[i];
                xr[i][m][r] = v;
                xb[row * LDB + (wid * 2 + i) * 16 + fl] = fb(v);
            }
        }
    __syncthreads();
}

// ---------------------------------------------------------------------------------------
// Fused 2-layer encoder, M=64/block, residual stream xr[2][4] (f32x4) doubles as the
// MFMA accumulator for Wo/FF2 (fused residual add). Two LDS buffers, 2 blocks/CU.
// ---------------------------------------------------------------------------------------
template<bool WORD>
__global__ __launch_bounds__(512, 4) void k_enc64(
    const int* __restrict__ inputs,
    const float* __restrict__ char_emb, const float* __restrict__ pos_emb,
    const unsigned short* __restrict__ qkvT, const unsigned short* __restrict__ woT,
    const unsigned short* __restrict__ w1T,  const unsigned short* __restrict__ w2T,
    const float* __restrict__ ln1s, const float* __restrict__ ln1b,
    const float* __restrict__ ln2s, const float* __restrict__ ln2b,
    const int* __restrict__ w2n, const int* __restrict__ wpos,
    float* __restrict__ NE, float* __restrict__ out)
{
    constexpr int T = WORD ? 16 : 8;
    const int blk = blockIdx.x, tid = threadIdx.x;
    const int lane = tid & 63, wid = tid >> 6;
    const int fl = lane & 15, fh = lane >> 4;
    __shared__ __attribute__((aligned(16))) unsigned short xb[64 * LDB];  // bf16 A-operand
    __shared__ __attribute__((aligned(16))) unsigned short SS[64 * LDB];  // Q/K/V/o/hidden
    __shared__ float red[64][8];
    __shared__ float mrow[64], srow[64];
    __shared__ int ch[64];

    const int wl = WORD ? (tid >> 7) : (tid >> 6);
    const int hh = WORD ? ((tid >> 4) & 7) : ((tid >> 3) & 7);
    const int tt = WORD ? (tid & 15) : (tid & 7);
    const int arow = wl * T + tt;

    f32x4 xr[2][4];   // f32 residual stream == MFMA accumulator layout [i][m][r]

    if (WORD) {
        if (tid < 64) ch[tid] = inputs[blk * 64 + tid];
        __syncthreads();
#pragma unroll
        for (int m = 0; m < 4; ++m)
#pragma unroll
            for (int r = 0; r < 4; ++r) {
                int row = m * 16 + fh * 4 + r;
#pragma unroll
                for (int i = 0; i < 2; ++i) {
                    int col = (wid * 2 + i) * 16 + fl;
                    float v = char_emb[(size_t)ch[row] * 256 + col] + pos_emb[(row & 15) * 256 + col];
                    xr[i][m][r] = v;
                    xb[row * LDB + col] = fb(v);
                }
            }
    } else {
#pragma unroll
        for (int m = 0; m < 4; ++m)
#pragma unroll
            for (int r = 0; r < 4; ++r) {
                int row = m * 16 + fh * 4 + r;
#pragma unroll
                for (int i = 0; i < 2; ++i) {
                    int col = (wid * 2 + i) * 16 + fl;
                    float v = NE[((size_t)blk * 64 + row) * 256 + col];
                    xr[i][m][r] = v;
                    xb[row * LDB + col] = fb(v);
                }
            }
    }
    __syncthreads();

    for (int l = 0; l < 2; ++l) {
        const unsigned short* wq = qkvT + (size_t)l * 196608;
        const unsigned short* wk = wq + 65536;
        const unsigned short* wv = wq + 131072;
        const unsigned short* wo = woT + (size_t)l * 65536;
        const unsigned short* w1 = w1T + (size_t)l * 262144;
        const unsigned short* w2 = w2T + (size_t)l * 262144;

        float q[32], p[T];

        // ---- Q -> SS; q -> regs ----
        { f32x4 acc[2][4] = {}; mm64<2, 8>(xb, wq, 256, 0, acc, wid * 2, lane); store_bf16<2, false>(acc, SS, wid * 2, lane); }
        __syncthreads();
#pragma unroll
        for (int db = 0; db < 4; ++db) {
            short8 qv = *(const short8*)&SS[arow * LDB + hh * 32 + db * 8];
#pragma unroll
            for (int j = 0; j < 8; ++j) q[db * 8 + j] = bu((unsigned short)qv[j]);
        }
        __syncthreads();

        // ---- K -> SS; scores + softmax -> p[] regs ----
        { f32x4 acc[2][4] = {}; mm64<2, 8>(xb, wk, 256, 0, acc, wid * 2, lane); store_bf16<2, false>(acc, SS, wid * 2, lane); }
        __syncthreads();
        {
            float mx = -1e30f;
#pragma unroll
            for (int s = 0; s < T; ++s) {
                float dot = 0.f;
#pragma unroll
                for (int db = 0; db < 4; ++db) {
                    short8 kv = *(const short8*)&SS[(wl * T + s) * LDB + hh * 32 + db * 8];
#pragma unroll
                    for (int j = 0; j < 8; ++j) dot += q[db * 8 + j] * bu((unsigned short)kv[j]);
                }
                dot *= 0.17677669529663687f;
                if (WORD && ch[wl * 16 + s] == 0) dot = -1e9f;   // key-pad mask
                p[s] = dot; mx = fmaxf(mx, dot);
            }
            float sum = 0.f;
#pragma unroll
            for (int s = 0; s < T; ++s) { p[s] = __expf(p[s] - mx); sum += p[s]; }
            float inv = 1.f / sum;
#pragma unroll
            for (int s = 0; s < T; ++s) p[s] *= inv;
        }
        __syncthreads();

        // ---- V -> SS; PV -> o regs; o -> SS own cell ----
        { f32x4 acc[2][4] = {}; mm64<2, 8>(xb, wv, 256, 0, acc, wid * 2, lane); store_bf16<2, false>(acc, SS, wid * 2, lane); }
        __syncthreads();
        {
            float o[32];
#pragma unroll
            for (int j = 0; j < 32; ++j) o[j] = 0.f;
#pragma unroll
            for (int s = 0; s < T; ++s) {
                float ps = p[s];
#pragma unroll
                for (int db = 0; db < 4; ++db) {
                    short8 vv = *(const short8*)&SS[(wl * T + s) * LDB + hh * 32 + db * 8];
#pragma unroll
                    for (int j = 0; j < 8; ++j) o[db * 8 + j] += ps * bu((unsigned short)vv[j]);
                }
            }
            __syncthreads();                       // all V reads complete
#pragma unroll
            for (int db = 0; db < 4; ++db) {
                short8 ov;
#pragma unroll
                for (int j = 0; j < 8; ++j) ov[j] = (short)fb(o[db * 8 + j]);
                *(short8*)&SS[arow * LDB + hh * 32 + db * 8] = ov;   // own cell
            }
        }
        __syncthreads();

        // ---- Wo: xr = SS(o) @ wo + xr  (residual fused via MFMA C-in) ; LN1 -> xb ----
        mm64<2, 8>(SS, wo, 256, 0, xr, wid * 2, lane);
        __syncthreads();
        ln_reg(xr, ln1s + l * 256, ln1b + l * 256, xb, red, mrow, srow, tid, fl, fh, wid);

        // ---- FF: 4 hidden chunks through SS; FF2 accumulates directly into xr ----
        for (int c = 0; c < 4; ++c) {
            {
                f32x4 acc1[2][4] = {};
                mm64<2, 8>(xb, w1 + (size_t)c * 65536, 256, 0, acc1, wid * 2, lane);
                store_bf16<2, true>(acc1, SS, wid * 2, lane);      // gelu(hidden chunk)
            }
            __syncthreads();
            mm64<2, 8>(SS, w2, 1024, c * 256, xr, wid * 2, lane);  // xr += chunk @ W2
            __syncthreads();
        }
        ln_reg(xr, ln2s + l * 256, ln2b + l * 256, xb, red, mrow, srow, tid, fl, fh, wid);
    }

    if (WORD) {
        // masked mean over chars (f32, shuffle over fh) -> NE[w2n*8+wpos]
#pragma unroll
        for (int m = 0; m < 4; ++m) {
            int cnt = 0;
#pragma unroll
            for (int c = 0; c < 16; ++c) if (ch[m * 16 + c] != 0) ++cnt;
            float inv = 1.f / (float)cnt;
#pragma unroll
            for (int i = 0; i < 2; ++i) {
                float s = 0.f;
#pragma unroll
                for (int r = 0; r < 4; ++r)
                    if (ch[m * 16 + fh * 4 + r] != 0) s += xr[i][m][r];
                s += __shfl_xor(s, 16, 64);
                s += __shfl_xor(s, 32, 64);
                if (fh == 0) {
                    int wg = blk * 4 + m;
                    size_t nrow = (size_t)w2n[wg] * 8 + wpos[wg];
                    NE[nrow * 256 + (wid * 2 + i) * 16 + fl] = s * inv;
                }
            }
        }
    } else {
        // np2-masked mean over 8 slots (pristine NE) -> out
#pragma unroll
        for (int m = 0; m < 4; ++m)
#pragma unroll
            for (int i = 0; i < 2; ++i) {
                int col = (wid * 2 + i) * 16 + fl;
                float s = 0.f, c = 0.f;
#pragma unroll
                for (int r = 0; r < 4; ++r) {
                    int row = m * 16 + fh * 4 + r;
                    float nev = NE[((size_t)blk * 64 + row) * 256 + col];
                    if (nev != 0.f) { s += xr[i][m][r]; c += 1.f; }
                }
                s += __shfl_xor(s, 16, 64);
                c += __shfl_xor(c, 16, 64);
                if ((fh & 1) == 0) {
                    int name = blk * 8 + 2 * m + (fh >> 1);
                    out[(size_t)name * 256 + col] = (c > 0.f) ? s / c : 0.f;
                }
            }
    }
}

// =======================================================================================
extern "C" void kernel_launch(void* const* d_in, const int* in_sizes, int n_in,
                              void* d_out, int out_size, void* d_ws, size_t ws_size,
                              hipStream_t stream) {
    float* out = (float*)d_out;

    const int* inputs    = (const int*)d_in[0];
    const int* w2n       = (const int*)d_in[1];
    const int* wpos      = (const int*)d_in[2];
    const float* char_emb = (const float*)d_in[3];
    const float* pos_emb  = (const float*)d_in[4];
    const float* we_Wqkv = (const float*)d_in[5];
    const float* we_Wo   = (const float*)d_in[6];
    const float* we_ln1s = (const float*)d_in[7];
    const float* we_ln1b = (const float*)d_in[8];
    const float* we_W1   = (const float*)d_in[9];
    const float* we_W2   = (const float*)d_in[10];
    const float* we_ln2s = (const float*)d_in[11];
    const float* we_ln2b = (const float*)d_in[12];
    const float* ne_Wqkv = (const float*)d_in[13];
    const float* ne_Wo   = (const float*)d_in[14];
    const float* ne_ln1s = (const float*)d_in[15];
    const float* ne_ln1b = (const float*)d_in[16];
    const float* ne_W1   = (const float*)d_in[17];
    const float* ne_W2   = (const float*)d_in[18];
    const float* ne_ln2s = (const float*)d_in[19];
    const float* ne_ln2b = (const float*)d_in[20];

    char* ws = (char*)d_ws;
    size_t off = 0;
    auto alloc = [&](size_t bytes) { void* p = ws + off; off += (bytes + 255) & ~(size_t)255; return p; };
    float* NE = (float*)alloc((size_t)16384 * 256 * 4);
    unsigned short* qkvT_we = (unsigned short*)alloc((size_t)2 * 196608 * 2);
    unsigned short* woT_we  = (unsigned short*)alloc((size_t)2 * 65536 * 2);
    unsigned short* w1T_we  = (unsigned short*)alloc((size_t)2 * 262144 * 2);
    unsigned short* w2T_we  = (unsigned short*)alloc((size_t)2 * 262144 * 2);
    unsigned short* qkvT_ne = (unsigned short*)alloc((size_t)2 * 196608 * 2);
    unsigned short* woT_ne  = (unsigned short*)alloc((size_t)2 * 65536 * 2);
    unsigned short* w1T_ne  = (unsigned short*)alloc((size_t)2 * 262144 * 2);
    unsigned short* w2T_ne  = (unsigned short*)alloc((size_t)2 * 262144 * 2);

    for (int l = 0; l < 2; ++l) {
        k_wt<<<(196608 + 255) / 256, 256, 0, stream>>>(we_Wqkv + (size_t)l * 196608, qkvT_we + (size_t)l * 196608, 256, 768);
        k_wt<<<(65536  + 255) / 256, 256, 0, stream>>>(we_Wo   + (size_t)l * 65536,  woT_we  + (size_t)l * 65536,  256, 256);
        k_wt<<<(262144 + 255) / 256, 256, 0, stream>>>(we_W1   + (size_t)l * 262144, w1T_we  + (size_t)l * 262144, 256, 1024);
        k_wt<<<(262144 + 255) / 256, 256, 0, stream>>>(we_W2   + (size_t)l * 262144, w2T_we  + (size_t)l * 262144, 1024, 256);
        k_wt<<<(196608 + 255) / 256, 256, 0, stream>>>(ne_Wqkv + (size_t)l * 196608, qkvT_ne + (size_t)l * 196608, 256, 768);
        k_wt<<<(65536  + 255) / 256, 256, 0, stream>>>(ne_Wo   + (size_t)l * 65536,  woT_ne  + (size_t)l * 65536,  256, 256);
        k_wt<<<(262144 + 255) / 256, 256, 0, stream>>>(ne_W1   + (size_t)l * 262144, w1T_ne  + (size_t)l * 262144, 256, 1024);
        k_wt<<<(262144 + 255) / 256, 256, 0, stream>>>(ne_W2   + (size_t)l * 262144, w2T_ne  + (size_t)l * 262144, 1024, 256);
    }

    (void)hipMemsetAsync(NE, 0, (size_t)16384 * 256 * 4, stream);

    k_enc64<true><<<2304, 512, 0, stream>>>(inputs, char_emb, pos_emb,
                                            qkvT_we, woT_we, w1T_we, w2T_we,
                                            we_ln1s, we_ln1b, we_ln2s, we_ln2b,
                                            w2n, wpos, NE, nullptr);

    k_enc64<false><<<256, 512, 0, stream>>>(nullptr, nullptr, nullptr,
                                            qkvT_ne, woT_ne, w1T_ne, w2T_ne,
                                            ne_ln1s, ne_ln1b, ne_ln2s, ne_ln2b,
                                            nullptr, nullptr, NE, out);
}